// Round 13
// baseline (107.022 us; speedup 1.0000x reference)
//
#include <hip/hip_runtime.h>
#include <hip/hip_bf16.h>
#include <math.h>

#define S_LEN 2048
#define DMODEL 1024
#define NHEADS 16
#define DHEAD 64
#define NBATCH 2
#define MROWS (NBATCH * S_LEN)   // 4096

typedef float f32x4 __attribute__((ext_vector_type(4)));
typedef unsigned short u16x8 __attribute__((ext_vector_type(8)));
typedef __bf16 bf16x8 __attribute__((ext_vector_type(8)));

__device__ __forceinline__ f32x4 mfma16(u16x8 a, u16x8 b, f32x4 c) {
    return __builtin_amdgcn_mfma_f32_16x16x32_bf16(
        __builtin_bit_cast(bf16x8, a), __builtin_bit_cast(bf16x8, b), c, 0, 0, 0);
}

// f32 -> bf16 round-to-nearest-even
__device__ __forceinline__ unsigned short f2bf(float f) {
    unsigned int u = __builtin_bit_cast(unsigned int, f);
    u += 0x7FFFu + ((u >> 16) & 1u);
    return (unsigned short)(u >> 16);
}

// packed f32x2 -> bf16x2 (RTNE), single HW instruction; low16 = lo
__device__ __forceinline__ unsigned int cvtpk(float lo, float hi) {
    unsigned int r;
    asm("v_cvt_pk_bf16_f32 %0, %1, %2" : "=v"(r) : "v"(lo), "v"(hi));
    return r;
}

// async global->LDS, 16B per lane; lds dest = wave-uniform base + lane*16
__device__ __forceinline__ void gl16(const void* g, void* l) {
    __builtin_amdgcn_global_load_lds(
        (const __attribute__((address_space(1))) unsigned int*)g,
        (__attribute__((address_space(3))) unsigned int*)l, 16, 0, 0);
}

// counted-vmcnt barrier: wait N outstanding vmem, then raw barrier.
#define PIPE_BAR_12() do { \
    asm volatile("s_waitcnt vmcnt(12)" ::: "memory"); \
    __builtin_amdgcn_sched_barrier(0); \
    __builtin_amdgcn_s_barrier(); \
    __builtin_amdgcn_sched_barrier(0); } while (0)
#define PIPE_BAR_6() do { \
    asm volatile("s_waitcnt vmcnt(6)" ::: "memory"); \
    __builtin_amdgcn_sched_barrier(0); \
    __builtin_amdgcn_s_barrier(); \
    __builtin_amdgcn_sched_barrier(0); } while (0)
#define PIPE_BAR_0() do { \
    asm volatile("s_waitcnt vmcnt(0)" ::: "memory"); \
    __builtin_amdgcn_sched_barrier(0); \
    __builtin_amdgcn_s_barrier(); \
    __builtin_amdgcn_sched_barrier(0); } while (0)

// ---------------------------------------------------------------- cvt + pos
// blocks 0..2047: X. 2048..4095: Wq,Wk,Wv,Wo. 4096..4607: pos table.
__global__ __launch_bounds__(256) void cvt5(
    const float* __restrict__ X, const float* __restrict__ Wq,
    const float* __restrict__ Wk, const float* __restrict__ Wv,
    const float* __restrict__ Wo,
    unsigned short* __restrict__ Xbf, unsigned short* __restrict__ Wbf,
    float* __restrict__ pos)
{
    int b = blockIdx.x;
    if (b >= 4096) {
        int i = (b - 4096) * 256 + threadIdx.x;
        int s = i >> 6, d = i & 63;
        float theta = powf(10000.0f, (2.0f * (float)d) / 64.0f);
        float x = (float)s / theta;
        float v = (d & 1) ? cosf(x) : sinf(x);
        pos[i] = (s == 0) ? 0.0f : v;
        return;
    }
    const float* s; unsigned short* d; int t;
    if (b < 2048) { s = X; d = Xbf; t = b * 256 + threadIdx.x; }
    else {
        int z = (b - 2048) >> 9, bb = (b - 2048) & 511;
        s = (z == 0) ? Wq : (z == 1) ? Wk : (z == 2) ? Wv : Wo;
        d = Wbf + (z << 20);
        t = bb * 256 + threadIdx.x;
    }
    float4 a = *((const float4*)s + t * 2);
    float4 c = *((const float4*)s + t * 2 + 1);
    u16x8 o;
    o[0] = f2bf(a.x); o[1] = f2bf(a.y); o[2] = f2bf(a.z); o[3] = f2bf(a.w);
    o[4] = f2bf(c.x); o[5] = f2bf(c.y); o[6] = f2bf(c.z); o[7] = f2bf(c.w);
    *((u16x8*)d + t) = o;
}

// ---------------------------------------------------------------- QKV GEMM (bf16 in)
// 2-wave blocks, 128x64 tile, grid (32, 48): y>>4 selects Q/K/V, (y&15) the
// 64-col N panel. BK=32, 3-buffer counted vmcnt(6) pipeline, 12KB/buffer ->
// 36KB LDS -> 4 blocks/CU (1.5 generations instead of 3).
// Swizzle (64B rows, 4 chunks): chunk = lg ^ (row&3) ^ ((row>>2)&3); <=2-way.
__global__ __launch_bounds__(128) void gemm_qkv(
    const unsigned short* __restrict__ Xbf, const unsigned short* __restrict__ Wbf,
    const float* __restrict__ pos,
    unsigned short* __restrict__ qb, unsigned short* __restrict__ kb,
    unsigned short* __restrict__ vt)
{
    const int y = blockIdx.y;
    const int z = y >> 4;
    const unsigned short* __restrict__ W = Wbf + (z << 20);
    __shared__ unsigned short L[3][6144];   // 12KB x 3 = 36KB (A 8KB + B 4KB)
    const int t = threadIdx.x;              // 0..127
    const int lane = t & 63;
    const int w = t >> 6;                   // 0..1
    const int m0 = blockIdx.x * 128;
    const int n0 = (y & 15) * 64;
    const int ll = lane & 15, lg = lane >> 4;
    const int r16 = lane >> 2, c4 = lane & 3;                 // stage decomposition
    const int swzr = (r16 & 3) ^ ((r16 >> 2) & 3);            // stage-side swizzle
    const int swzll = (ll & 3) ^ ((ll >> 2) & 3);             // read-side swizzle

    f32x4 acc[4][4] = {};

    // running global stage pointers (advance 32 elems per stage call)
    const unsigned short* gA[4];
    const unsigned short* gB[2];
    #pragma unroll
    for (int i = 0; i < 4; i++)
        gA[i] = Xbf + (m0 + w * 64 + i * 16 + r16) * 1024 + ((c4 ^ swzr) * 8);
    #pragma unroll
    for (int i = 0; i < 2; i++)
        gB[i] = W + (n0 + w * 32 + i * 16 + r16) * 1024 + ((c4 ^ swzr) * 8);

    const int sw = ((lg ^ swzll) & 3) * 16;   // read chunk byte offset

    // 6 vmem instructions per wave per call; advances gA/gB by 32 elems
    auto stage = [&](unsigned short* Lb) {
        unsigned short* const dA = Lb + w * 2048;          // A rows [w*64, +64)
        unsigned short* const dB = Lb + 4096 + w * 1024;   // B rows [w*32, +32)
        #pragma unroll
        for (int i = 0; i < 4; i++) { gl16(gA[i], dA + i * 512); gA[i] += 32; }
        #pragma unroll
        for (int i = 0; i < 2; i++) { gl16(gB[i], dB + i * 512); gB[i] += 32; }
    };
    auto compute = [&](const unsigned short* Lb) {
        const char* const pA = (const char*)Lb + (w * 64 + ll) * 64 + sw;
        const char* const pB = (const char*)Lb + 8192 + ll * 64 + sw;
        u16x8 af[4], bfv[4];
        #pragma unroll
        for (int m = 0; m < 4; m++) af[m] = *(const u16x8*)(pA + m * 1024);
        #pragma unroll
        for (int n = 0; n < 4; n++) bfv[n] = *(const u16x8*)(pB + n * 1024);
        __builtin_amdgcn_s_setprio(1);
        #pragma unroll
        for (int m = 0; m < 4; m++)
            #pragma unroll
            for (int n = 0; n < 4; n++)
                acc[m][n] = mfma16(af[m], bfv[n], acc[m][n]);
        __builtin_amdgcn_s_setprio(0);
    };

    // prologue: stage t0->L0, t1->L1; wait t0 (t1's 6 stay in flight)
    stage(L[0]);
    stage(L[1]);
    PIPE_BAR_6();
    // steady: t=0..29 (stage t+2, compute t, wait t+1); 32 K-steps total
    for (int tt = 0; tt < 10; tt++) {
        stage(L[2]); compute(L[0]); PIPE_BAR_6();
        stage(L[0]); compute(L[1]); PIPE_BAR_6();
        stage(L[1]); compute(L[2]); PIPE_BAR_6();
    }
    // t=30: compute L0 (staged as s30); drain s31; t=31: compute L1
    compute(L[0]); PIPE_BAR_0();
    compute(L[1]);

    if (z == 2) {
        // V^T: r=0..3 are s-consecutive -> one packed u64 store per (m,n)
        #pragma unroll
        for (int m = 0; m < 4; m++) {
            const int row0 = m0 + w * 64 + m * 16 + lg * 4;
            const int b = row0 >> 11, s0 = row0 & 2047;
            #pragma unroll
            for (int n = 0; n < 4; n++) {
                const int c = n0 + n * 16 + ll;      // h*64 + d
                const int h = c >> 6, d = c & 63;
                unsigned long long pk =
                    (unsigned long long)cvtpk(acc[m][n][0], acc[m][n][1]) |
                    ((unsigned long long)cvtpk(acc[m][n][2], acc[m][n][3]) << 32);
                *(unsigned long long*)&vt[(((b * NHEADS + h) * 64) + d) * S_LEN + s0] = pk;
            }
        }
    } else {
        unsigned short* const dst = (z == 0) ? qb : kb;
        #pragma unroll
        for (int m = 0; m < 4; m++) {
            #pragma unroll
            for (int n = 0; n < 4; n++) {
                #pragma unroll
                for (int r = 0; r < 4; r++) {
                    const int row = m0 + w * 64 + m * 16 + lg * 4 + r;
                    const int c = n0 + n * 16 + ll;
                    const int b = row >> 11, s = row & 2047;
                    const int h = c >> 6, d = c & 63;
                    float v = acc[m][n][r] + pos[s * 64 + d];
                    // Q: fold 1/sqrt(d_k) * log2(e) so softmax can use exp2
                    if (z == 0) v *= 0.1803368801111244f;
                    dst[(((b * NHEADS + h) * S_LEN) + s) * 64 + d] = f2bf(v);
                }
            }
        }
    }
}

// ---------------------------------------------------------------- attention
// grid (16 qt, 32 bh), 8 waves x 512 thr, QBLK=128 (wave owns 16 q-rows).
// KVBLK=128: one barrier interval covers 128 KV rows (two 64-halves run
// back-to-back). K[2][128x64] + V^T[2][64x128] double-buffered (64KB) +
// per-wave P (16KB) = 80KB. Diagonal 128-tile peeled; waves 0-3 skip its
// fully-masked second half. Fixed-shift softmax exp2(sc).
__global__ __launch_bounds__(512, 4) void attn_kernel(
    const unsigned short* __restrict__ qb,
    const unsigned short* __restrict__ kb,
    const unsigned short* __restrict__ vt,
    unsigned short* __restrict__ attnb)
{
    __shared__ unsigned short Klds[2][128 * 64];   // 16KB each
    __shared__ unsigned short Vlds[2][64 * 128];   // 16KB each (row=d, 128 s-cols)
    __shared__ unsigned short Plds[8][16 * 64];    // per-wave 2KB; total 80KB

    const int bh = blockIdx.y;
    const int x = blockIdx.x;
    const int qt = (bh < 16) ? (15 - x) : x;      // pair long+short across halves

    const int lane = threadIdx.x & 63;
    const int w = threadIdx.x >> 6;               // 0..7
    const int lg = lane >> 4, ll = lane & 15;
    const int r8 = lane >> 3, ch = (lane & 7) ^ r8;
    const int r4 = lane >> 4, c16 = lane & 15;    // V-stage decomposition

    const unsigned short* Q = qb + bh * (S_LEN * 64);
    const unsigned short* K = kb + bh * (S_LEN * 64);
    const unsigned short* V = vt + bh * (64 * S_LEN);
    const int q0 = qt * 128 + w * 16;             // wave q-base

    u16x8 qf0 = *(const u16x8*)(Q + (q0 + ll) * 64 + lg * 8);
    u16x8 qf1 = *(const u16x8*)(Q + (q0 + ll) * 64 + 32 + lg * 8);

    f32x4 o_acc[4] = {};
    float l_part = 0.0f;

    // ---- precomputed LDS byte addresses ----
    const int sw0 = ((0 * 4 + lg) ^ (ll & 7)) * 16;
    const int sw1 = ((1 * 4 + lg) ^ (ll & 7)) * 16;
    // K read (row stride 128B): base + ll*128 + sw ; half1 = +8192 ; f-stride 2048
    const char* kb0p0 = (const char*)&Klds[0][0] + ll * 128 + sw0;
    const char* kb0p1 = (const char*)&Klds[0][0] + ll * 128 + sw1;
    const char* kb1p0 = (const char*)&Klds[1][0] + ll * 128 + sw0;
    const char* kb1p1 = (const char*)&Klds[1][0] + ll * 128 + sw1;
    // V read (row stride 256B): base + ll*256 + sw ; half1 = +128 ; f-stride 4096
    const char* vb0p0 = (const char*)&Vlds[0][0] + ll * 256 + sw0;
    const char* vb0p1 = (const char*)&Vlds[0][0] + ll * 256 + sw1;
    const char* vb1p0 = (const char*)&Vlds[1][0] + ll * 256 + sw0;
    const char* vb1p1 = (const char*)&Vlds[1][0] + ll * 256 + sw1;
    // P write: addr = ((ll*128+lg*8) ^ (E&16)) + ((f*32) ^ (E&96)),  E=(ll&7)<<4
    const int E = (ll & 7) << 4;
    char* pwb = (char*)&Plds[w][0] + (((ll * 128) + lg * 8) ^ (E & 16));
    const int pw_o0 = 0 ^ (E & 96), pw_o1 = 32 ^ (E & 96);
    const int pw_o2 = 64 ^ (E & 96), pw_o3 = 96 ^ (E & 96);
    const char* pr0 = (const char*)&Plds[w][0] + ll * 128 + sw0;
    const char* pr1 = (const char*)&Plds[w][0] + ll * 128 + sw1;
    // staging: K rows [w*16, +16) = 2 gl16; V rows [w*8, +8) = 2 gl16 (4 rows each)
    unsigned short* kd0 = &Klds[0][(w * 16) * 64];
    unsigned short* kd1 = &Klds[1][(w * 16) * 64];
    unsigned short* vd0 = &Vlds[0][(w * 8) * 128];
    unsigned short* vd1 = &Vlds[1][(w * 8) * 128];
    const unsigned short* gk  = K + (w * 16 + r8) * 64 + ch * 8;
    const unsigned short* gva = V + (w * 8 + r4) * S_LEN + ((c16 ^ r4) * 8);
    const unsigned short* gvb = V + (w * 8 + 4 + r4) * S_LEN + ((c16 ^ (4 + r4)) * 8);
    // diagonal thresholds: half0 thr = dthr, half1 thr = dthr - 64
    const int dthr = w * 16 + ll - lg * 4;

    auto stage2 = [&](unsigned short* kd, unsigned short* vd) {
        gl16(gk, kd);
        gl16(gk + 512, kd + 512);      // K rows +8
        gl16(gva, vd);
        gl16(gvb, vd + 512);           // V rows +4
        gk += 128 * 64;                // next 128-KV tile
        gva += 128;
        gvb += 128;
    };

    auto tile_body = [&](const char* kp0, const char* kp1,
                         const char* vp0, const char* vp1, bool masked, int thr) {
        f32x4 sc[4] = {};
        __builtin_amdgcn_s_setprio(1);
        #pragma unroll
        for (int f = 0; f < 4; f++) {
            const u16x8 kfa = *(const u16x8*)(kp0 + f * 2048);
            sc[f] = mfma16(kfa, qf0, sc[f]);
            const u16x8 kfb = *(const u16x8*)(kp1 + f * 2048);
            sc[f] = mfma16(kfb, qf1, sc[f]);
        }
        __builtin_amdgcn_s_setprio(0);
        if (masked) {
            #pragma unroll
            for (int f = 0; f < 4; f++)
                #pragma unroll
                for (int r = 0; r < 4; r++)
                    if (f * 16 + r > thr) sc[f][r] = -1.0e9f;
        }
        float ts = 0.0f;
        #pragma unroll
        for (int f = 0; f < 4; f++)
            #pragma unroll
            for (int r = 0; r < 4; r++) {
                const float p = __builtin_amdgcn_exp2f(sc[f][r]);
                sc[f][r] = p;
                ts += p;
            }
        l_part += ts;
        *(unsigned long long*)(pwb + pw_o0) =
            (unsigned long long)cvtpk(sc[0][0], sc[0][1]) | ((unsigned long long)cvtpk(sc[0][2], sc[0][3]) << 32);
        *(unsigned long long*)(pwb + pw_o1) =
            (unsigned long long)cvtpk(sc[1][0], sc[1][1]) | ((unsigned long long)cvtpk(sc[1][2], sc[1][3]) << 32);
        *(unsigned long long*)(pwb + pw_o2) =
            (unsigned long long)cvtpk(sc[2][0], sc[2][1]) | ((unsigned long long)cvtpk(sc[2][2], sc[2][3]) << 32);
        *(unsigned long long*)(pwb + pw_o3) =
            (unsigned long long)cvtpk(sc[3][0], sc[3][1]) | ((unsigned long long)cvtpk(sc[3][2], sc[3][3]) << 32);
        const u16x8 pf0 = *(const u16x8*)pr0;
        const u16x8 pf1 = *(const u16x8*)pr1;
        __builtin_amdgcn_s_setprio(1);
        #pragma unroll
        for (int f = 0; f < 4; f++) {
            o_acc[f] = mfma16(pf0, *(const u16x8*)(vp0 + f * 4096), o_acc[f]);
            o_acc[f] = mfma16(pf1, *(const u16x8*)(vp1 + f * 4096), o_acc[f]);
        }
        __builtin_amdgcn_s_setprio(0);
    };

    // body over one 128-KV buffer: two 64-halves
    auto body128_full = [&](const char* kp0, const char* kp1,
                            const char* vp0, const char* vp1) {
        tile_body(kp0, kp1, vp0, vp1, false, 0);
        tile_body(kp0 + 8192, kp1 + 8192, vp0 + 128, vp1 + 128, false, 0);
    };
    auto body128_diag = [&](const char* kp0, const char* kp1,
                            const char* vp0, const char* vp1) {
        tile_body(kp0, kp1, vp0, vp1, true, dthr);
        if (w >= 4)   // waves 0-3: second half fully masked
            tile_body(kp0 + 8192, kp1 + 8192, vp0 + 128, vp1 + 128, true, dthr - 64);
    };

    stage2(kd0, vd0);                      // tile 0 -> buf0
    __syncthreads();                       // buf0 ready

    int p = 0;
    while (p + 2 <= qt) {                  // two full 128-tiles
        stage2(kd1, vd1);                  // tile p+1 -> buf1
        body128_full(kb0p0, kb0p1, vb0p0, vb0p1);
        __syncthreads();                   // drains stage(p+1); buf1 ready
        stage2(kd0, vd0);                  // tile p+2 -> buf0
        body128_full(kb1p0, kb1p1, vb1p0, vb1p1);
        __syncthreads();                   // drains stage(p+2); buf0 ready
        p += 2;
    }
    if (p < qt) {                          // one full tile (p, buf0) + diag (buf1)
        stage2(kd1, vd1);                  // tile qt -> buf1
        body128_full(kb0p0, kb0p1, vb0p0, vb0p1);
        __syncthreads();
        body128_diag(kb1p0, kb1p1, vb1p0, vb1p1);
    } else {                               // diag in buf0
        body128_diag(kb0p0, kb0p1, vb0p0, vb0p1);
    }

    // one-time l reduction: lane (lg,ll) holds partial over its kv-subset of q=ll
    l_part += __shfl_xor(l_part, 16);
    l_part += __shfl_xor(l_part, 32);

    const int bb = bh >> 4, h = bh & 15;
    float lr0 = 1.0f / __shfl(l_part, lg * 4 + 0);
    float lr1 = 1.0f / __shfl(l_part, lg * 4 + 1);
    float lr2 = 1.0f / __shfl(l_part, lg * 4 + 2);
    float lr3 = 1.0f / __shfl(l_part, lg * 4 + 3);
    #pragma unroll
    for (int f = 0; f < 4; f++) {
        const int colbase = h * 64 + f * 16 + ll;
        attnb[(bb * S_LEN + q0 + lg * 4 + 0) * DMODEL + colbase] = f2bf(o_acc[f][0] * lr0);
        attnb[(bb * S_LEN + q0 + lg * 4 + 1) * DMODEL + colbase] = f2bf(o_acc[f][1] * lr1);
        attnb[(bb * S_LEN + q0 + lg * 4 + 2) * DMODEL + colbase] = f2bf(o_acc[f][2] * lr2);
        attnb[(bb * S_LEN + q0 + lg * 4 + 3) * DMODEL + colbase] = f2bf(o_acc[f][3] * lr3);
    }
}

// ---------------------------------------------------------------- out GEMM
// out = attn @ Wo^T + X. 3-buffer counted-vmcnt pipeline, 2-wave 128x64.
__global__ __launch_bounds__(128) void gemm_out(
    const unsigned short* __restrict__ Abf,
    const unsigned short* __restrict__ Wbf,
    const float* __restrict__ X,
    float* __restrict__ out)
{
    const unsigned short* __restrict__ W = Wbf + (3u << 20);
    __shared__ unsigned short L[3][192 * 64];   // 72KB
    const int t = threadIdx.x;
    const int lane = t & 63;
    const int w = t >> 6;
    const int m0 = blockIdx.x * 128;
    const int n0 = blockIdx.y * 64;
    const int ll = lane & 15, lg = lane >> 4;
    const int r8 = lane >> 3, ch = (lane & 7) ^ r8;

    f32x4 acc[4][4] = {};

    const unsigned short* gA[8];
    const unsigned short* gB[4];
    #pragma unroll
    for (int i = 0; i < 8; i++) gA[i] = Abf + (m0 + w * 64 + i * 8 + r8) * 1024 + ch * 8;
    #pragma unroll
    for (int i = 0; i < 4; i++) gB[i] = W + (n0 + w * 32 + i * 8 + r8) * 1024 + ch * 8;

    const int sw0 = ((0 * 4 + lg) ^ (ll & 7)) * 16;
    const int sw1 = ((1 * 4 + lg) ^ (ll & 7)) * 16;

    auto stage = [&](unsigned short* Lb) {
        unsigned short* const dA = Lb + (w * 64) * 64;
        unsigned short* const dB = Lb + 128 * 64 + (w * 32) * 64;
        #pragma unroll
        for (int i = 0; i < 8; i++) { gl16(gA[i], dA + i * 8 * 64); gA[i] += 64; }
        #pragma unroll
        for (int i = 0; i < 4; i++) { gl16(gB[i], dB + i * 8 * 64); gB[i] += 64; }
    };
    auto compute = [&](const unsigned short* Lb) {
        const char* const pA0 = (const char*)Lb + (w * 64 + ll) * 128 + sw0;
        const char* const pA1 = (const char*)Lb + (w * 64 + ll) * 128 + sw1;
        const char* const pB0 = (const char*)Lb + 16384 + ll * 128 + sw0;
        const char* const pB1 = (const char*)Lb + 16384 + ll * 128 + sw1;
        u16x8 af[4], bfv[4];
        #pragma unroll
        for (int m = 0; m < 4; m++) af[m] = *(const u16x8*)(pA0 + m * 2048);
        #pragma unroll
        for (int n = 0; n < 4; n++) bfv[n] = *(const u16x8*)(pB0 + n * 2048);
        __builtin_amdgcn_s_setprio(1);
        #pragma unroll
        for (int m = 0; m < 4; m++)
            #pragma unroll
            for (int n = 0; n < 4; n++)
                acc[m][n] = mfma16(af[m], bfv[n], acc[m][n]);
        __builtin_amdgcn_s_setprio(0);
        #pragma unroll
        for (int m = 0; m < 4; m++) af[m] = *(const u16x8*)(pA1 + m * 2048);
        #pragma unroll
        for (int n = 0; n < 4; n++) bfv[n] = *(const u16x8*)(pB1 + n * 2048);
        __builtin_amdgcn_s_setprio(1);
        #pragma unroll
        for (int m = 0; m < 4; m++)
            #pragma unroll
            for (int n = 0; n < 4; n++)
                acc[m][n] = mfma16(af[m], bfv[n], acc[m][n]);
        __builtin_amdgcn_s_setprio(0);
    };

    stage(L[0]);
    stage(L[1]);
    PIPE_BAR_12();
    for (int tt = 0; tt < 4; tt++) {
        stage(L[2]); compute(L[0]); PIPE_BAR_12();
        stage(L[0]); compute(L[1]); PIPE_BAR_12();
        stage(L[1]); compute(L[2]); PIPE_BAR_12();
    }
    stage(L[2]); compute(L[0]); PIPE_BAR_12();
    stage(L[0]); compute(L[1]); PIPE_BAR_12();
    compute(L[2]); PIPE_BAR_0();
    compute(L[0]);

    #pragma unroll
    for (int m = 0; m < 4; m++)
        #pragma unroll
        for (int n = 0; n < 4; n++)
            #pragma unroll
            for (int r = 0; r < 4; r++) {
                const int row = m0 + w * 64 + m * 16 + lg * 4 + r;
                const int col = n0 + n * 16 + ll;
                out[row * 1024 + col] = acc[m][n][r] + X[row * 1024 + col];
            }
}

// ---------------------------------------------------------------- launch
extern "C" void kernel_launch(void* const* d_in, const int* in_sizes, int n_in,
                              void* d_out, int out_size, void* d_ws, size_t ws_size,
                              hipStream_t stream) {
    const float* X  = (const float*)d_in[0];
    const float* Wq = (const float*)d_in[1];
    const float* Wk = (const float*)d_in[2];
    const float* Wv = (const float*)d_in[3];
    const float* Wo = (const float*)d_in[4];
    float* out = (float*)d_out;

    char* ws = (char*)d_ws;
    float*          pos  = (float*)(ws);                                   // 512 KB
    unsigned short* Xbf  = (unsigned short*)(ws + (512u << 10));           // 8 MB (reused as attb)
    unsigned short* Wbf  = (unsigned short*)(ws + (512u << 10) + (8u  << 20));  // 8 MB (4 stacked)
    unsigned short* qb   = (unsigned short*)(ws + (512u << 10) + (16u << 20));
    unsigned short* kb   = (unsigned short*)(ws + (512u << 10) + (24u << 20));
    unsigned short* vt   = (unsigned short*)(ws + (512u << 10) + (32u << 20));
    unsigned short* attb = Xbf;   // Xbf dead after gemm_qkv; reuse for attn output

    cvt5<<<dim3(4608), dim3(256), 0, stream>>>(X, Wq, Wk, Wv, Wo, Xbf, Wbf, pos);
    gemm_qkv<<<dim3(32, 48), dim3(128), 0, stream>>>(Xbf, Wbf, pos, qb, kb, vt);
    attn_kernel<<<dim3(16, 32), dim3(512), 0, stream>>>(qb, kb, vt, attb);
    gemm_out<<<dim3(32, 16), dim3(128), 0, stream>>>(attb, Wbf, X, out);
}

// Round 14
// 95.790 us; speedup vs baseline: 1.1172x; 1.1172x over previous
//
#include <hip/hip_runtime.h>
#include <hip/hip_bf16.h>
#include <math.h>

#define S_LEN 2048
#define DMODEL 1024
#define NHEADS 16
#define DHEAD 64
#define NBATCH 2
#define MROWS (NBATCH * S_LEN)   // 4096

typedef float f32x4 __attribute__((ext_vector_type(4)));
typedef unsigned short u16x8 __attribute__((ext_vector_type(8)));
typedef __bf16 bf16x8 __attribute__((ext_vector_type(8)));

__device__ __forceinline__ f32x4 mfma16(u16x8 a, u16x8 b, f32x4 c) {
    return __builtin_amdgcn_mfma_f32_16x16x32_bf16(
        __builtin_bit_cast(bf16x8, a), __builtin_bit_cast(bf16x8, b), c, 0, 0, 0);
}

// f32 -> bf16 round-to-nearest-even
__device__ __forceinline__ unsigned short f2bf(float f) {
    unsigned int u = __builtin_bit_cast(unsigned int, f);
    u += 0x7FFFu + ((u >> 16) & 1u);
    return (unsigned short)(u >> 16);
}

// packed f32x2 -> bf16x2 (RTNE), single HW instruction; low16 = lo
__device__ __forceinline__ unsigned int cvtpk(float lo, float hi) {
    unsigned int r;
    asm("v_cvt_pk_bf16_f32 %0, %1, %2" : "=v"(r) : "v"(lo), "v"(hi));
    return r;
}

// async global->LDS, 16B per lane; lds dest = wave-uniform base + lane*16
__device__ __forceinline__ void gl16(const void* g, void* l) {
    __builtin_amdgcn_global_load_lds(
        (const __attribute__((address_space(1))) unsigned int*)g,
        (__attribute__((address_space(3))) unsigned int*)l, 16, 0, 0);
}

// counted-vmcnt barrier: wait N outstanding vmem, then raw barrier.
#define PIPE_BAR_12() do { \
    asm volatile("s_waitcnt vmcnt(12)" ::: "memory"); \
    __builtin_amdgcn_sched_barrier(0); \
    __builtin_amdgcn_s_barrier(); \
    __builtin_amdgcn_sched_barrier(0); } while (0)
#define PIPE_BAR_0() do { \
    asm volatile("s_waitcnt vmcnt(0)" ::: "memory"); \
    __builtin_amdgcn_sched_barrier(0); \
    __builtin_amdgcn_s_barrier(); \
    __builtin_amdgcn_sched_barrier(0); } while (0)

// ---------------------------------------------------------------- cvt + pos
// blocks 0..2047: X. 2048..4095: Wq,Wk,Wv,Wo. 4096..4607: pos table.
__global__ __launch_bounds__(256) void cvt5(
    const float* __restrict__ X, const float* __restrict__ Wq,
    const float* __restrict__ Wk, const float* __restrict__ Wv,
    const float* __restrict__ Wo,
    unsigned short* __restrict__ Xbf, unsigned short* __restrict__ Wbf,
    float* __restrict__ pos)
{
    int b = blockIdx.x;
    if (b >= 4096) {
        int i = (b - 4096) * 256 + threadIdx.x;
        int s = i >> 6, d = i & 63;
        float theta = powf(10000.0f, (2.0f * (float)d) / 64.0f);
        float x = (float)s / theta;
        float v = (d & 1) ? cosf(x) : sinf(x);
        pos[i] = (s == 0) ? 0.0f : v;
        return;
    }
    const float* s; unsigned short* d; int t;
    if (b < 2048) { s = X; d = Xbf; t = b * 256 + threadIdx.x; }
    else {
        int z = (b - 2048) >> 9, bb = (b - 2048) & 511;
        s = (z == 0) ? Wq : (z == 1) ? Wk : (z == 2) ? Wv : Wo;
        d = Wbf + (z << 20);
        t = bb * 256 + threadIdx.x;
    }
    float4 a = *((const float4*)s + t * 2);
    float4 c = *((const float4*)s + t * 2 + 1);
    u16x8 o;
    o[0] = f2bf(a.x); o[1] = f2bf(a.y); o[2] = f2bf(a.z); o[3] = f2bf(a.w);
    o[4] = f2bf(c.x); o[5] = f2bf(c.y); o[6] = f2bf(c.z); o[7] = f2bf(c.w);
    *((u16x8*)d + t) = o;
}

// ---------------------------------------------------------------- QKV GEMM (bf16 in)
// 8-phase port: 256x256 tile, BK=64, 512 thr (8 waves, 2Mx4N), grid (16,12):
// y>>2 selects Q/K/V, (y&3) the 256-col N panel. LDS 2 x 64KB (A 32K + B 32K).
// Per K-tile: 4 phases {issue 1 stage-quarter of tile j+1 -> other buffer;
// ds_read quadrant frags; setprio(1) 16 MFMA setprio(0); s_barrier}; tile end
// = vmcnt(0)+barrier (only vmem wait). Race-free: next-tile buffer last read
// in tile j-1 (barrier'd); tile-end vmcnt(0)+barrier publishes all 8 loads.
__global__ __launch_bounds__(512) void gemm_qkv(
    const unsigned short* __restrict__ Xbf, const unsigned short* __restrict__ Wbf,
    const float* __restrict__ pos,
    unsigned short* __restrict__ qb, unsigned short* __restrict__ kb,
    unsigned short* __restrict__ vt)
{
    const int y = blockIdx.y;
    const int z = y >> 2;
    const unsigned short* __restrict__ W = Wbf + (z << 20);
    __shared__ unsigned short L[2][32768];   // 64KB per buffer: A 16384, B +16384
    const int t = threadIdx.x;               // 0..511
    const int lane = t & 63;
    const int w = t >> 6;                    // 0..7
    const int wm = w >> 2, wn = w & 3;
    const int m0 = blockIdx.x * 256;
    const int nb = (y & 3) * 256;
    const int ll = lane & 15, lg = lane >> 4;
    const int tr = t >> 3;                   // 0..63: row within each 64-row group
    const int ch = (t & 7) ^ (tr & 7);       // pre-swizzled source chunk

    f32x4 acc[8][4] = {};

    // running global stage pointers (advance 64 elems per K-tile)
    const unsigned short* gA[4];
    const unsigned short* gB[4];
    #pragma unroll
    for (int i = 0; i < 4; i++) {
        gA[i] = Xbf + (m0 + i * 64 + tr) * 1024 + ch * 8;
        gB[i] = W + (nb + i * 64 + tr) * 1024 + ch * 8;
    }

    const int sw0 = ((0 * 4 + lg) ^ (ll & 7)) * 16;
    const int sw1 = ((1 * 4 + lg) ^ (ll & 7)) * 16;
    // hoisted LDS read bases (byte offsets into a buffer)
    const int aBase = (wm * 128 + ll) * 128;            // + q*4096 + {0,2048} + sw
    const int bBase = 32768 + (wn * 64 + ll) * 128;     // + nf*2048 + sw

    // stage-quarters: each = 2 gl16/thread, one 64-row group each
    auto sqA01 = [&](unsigned short* Ln) {
        gl16(gA[0], Ln + (0 * 64 + w * 8) * 64); gA[0] += 64;
        gl16(gA[1], Ln + (1 * 64 + w * 8) * 64); gA[1] += 64;
    };
    auto sqA23 = [&](unsigned short* Ln) {
        gl16(gA[2], Ln + (2 * 64 + w * 8) * 64); gA[2] += 64;
        gl16(gA[3], Ln + (3 * 64 + w * 8) * 64); gA[3] += 64;
    };
    auto sqB01 = [&](unsigned short* Ln) {
        gl16(gB[0], Ln + 16384 + (0 * 64 + w * 8) * 64); gB[0] += 64;
        gl16(gB[1], Ln + 16384 + (1 * 64 + w * 8) * 64); gB[1] += 64;
    };
    auto sqB23 = [&](unsigned short* Ln) {
        gl16(gB[2], Ln + 16384 + (2 * 64 + w * 8) * 64); gB[2] += 64;
        gl16(gB[3], Ln + 16384 + (3 * 64 + w * 8) * 64); gB[3] += 64;
    };

    u16x8 bf[4][2];

    auto quad = [&](int q, const char* bA) {
        const char* pa = bA + aBase + q * 4096;
        u16x8 a00 = *(const u16x8*)(pa + sw0);
        u16x8 a01 = *(const u16x8*)(pa + sw1);
        u16x8 a10 = *(const u16x8*)(pa + 2048 + sw0);
        u16x8 a11 = *(const u16x8*)(pa + 2048 + sw1);
        __builtin_amdgcn_s_setprio(1);
        #pragma unroll
        for (int nf = 0; nf < 4; nf++) {
            acc[q * 2 + 0][nf] = mfma16(a00, bf[nf][0], acc[q * 2 + 0][nf]);
            acc[q * 2 + 1][nf] = mfma16(a10, bf[nf][0], acc[q * 2 + 1][nf]);
        }
        #pragma unroll
        for (int nf = 0; nf < 4; nf++) {
            acc[q * 2 + 0][nf] = mfma16(a01, bf[nf][1], acc[q * 2 + 0][nf]);
            acc[q * 2 + 1][nf] = mfma16(a11, bf[nf][1], acc[q * 2 + 1][nf]);
        }
        __builtin_amdgcn_s_setprio(0);
    };

    auto ktile = [&](const unsigned short* Lb, unsigned short* Ln, bool stg) {
        const char* bA = (const char*)Lb;
        const char* bB = (const char*)Lb;
        // phase 1: stage SQ0, load B frags (pinned for whole tile), quad 0
        if (stg) sqA01(Ln);
        #pragma unroll
        for (int nf = 0; nf < 4; nf++) {
            const char* p = bB + bBase + nf * 2048;
            bf[nf][0] = *(const u16x8*)(p + sw0);
            bf[nf][1] = *(const u16x8*)(p + sw1);
        }
        quad(0, bA);
        __builtin_amdgcn_s_barrier();
        // phase 2
        if (stg) sqA23(Ln);
        quad(1, bA);
        __builtin_amdgcn_s_barrier();
        // phase 3
        if (stg) sqB01(Ln);
        quad(2, bA);
        __builtin_amdgcn_s_barrier();
        // phase 4
        if (stg) sqB23(Ln);
        quad(3, bA);
        PIPE_BAR_0();
    };

    // prologue: stage tile 0 -> L[0]
    sqA01(L[0]); sqA23(L[0]); sqB01(L[0]); sqB23(L[0]);
    PIPE_BAR_0();
    // 16 K-tiles, alternating buffers; tile j stages j+1 (last stages none)
    #pragma unroll 1
    for (int tt = 0; tt < 8; tt++) {
        ktile(L[0], L[1], true);
        ktile(L[1], L[0], tt != 7);
    }

    if (z == 2) {
        // V^T: r=0..3 are s-consecutive -> one packed u64 store per (mf,nf)
        #pragma unroll
        for (int mf = 0; mf < 8; mf++) {
            const int row0 = m0 + wm * 128 + mf * 16 + lg * 4;
            const int b = row0 >> 11, s0 = row0 & 2047;
            #pragma unroll
            for (int nf = 0; nf < 4; nf++) {
                const int c = nb + wn * 64 + nf * 16 + ll;   // h*64 + d
                const int h = c >> 6, d = c & 63;
                unsigned long long pk =
                    (unsigned long long)cvtpk(acc[mf][nf][0], acc[mf][nf][1]) |
                    ((unsigned long long)cvtpk(acc[mf][nf][2], acc[mf][nf][3]) << 32);
                *(unsigned long long*)&vt[(((b * NHEADS + h) * 64) + d) * S_LEN + s0] = pk;
            }
        }
    } else {
        unsigned short* const dst = (z == 0) ? qb : kb;
        #pragma unroll
        for (int mf = 0; mf < 8; mf++) {
            #pragma unroll
            for (int nf = 0; nf < 4; nf++) {
                #pragma unroll
                for (int r = 0; r < 4; r++) {
                    const int row = m0 + wm * 128 + mf * 16 + lg * 4 + r;
                    const int c = nb + wn * 64 + nf * 16 + ll;
                    const int b = row >> 11, s = row & 2047;
                    const int h = c >> 6, d = c & 63;
                    float v = acc[mf][nf][r] + pos[s * 64 + d];
                    // Q: fold 1/sqrt(d_k) * log2(e) so softmax can use exp2
                    if (z == 0) v *= 0.1803368801111244f;
                    dst[(((b * NHEADS + h) * S_LEN) + s) * 64 + d] = f2bf(v);
                }
            }
        }
    }
}

// ---------------------------------------------------------------- attention
// grid (16 qt, 32 bh), 8 waves x 512 thr, QBLK=128 (wave owns 16 q-rows).
// KVBLK=128: one barrier interval covers 128 KV rows (two 64-halves run
// back-to-back). K[2][128x64] + V^T[2][64x128] double-buffered (64KB) +
// per-wave P (16KB) = 80KB. Diagonal 128-tile peeled; waves 0-3 skip its
// fully-masked second half. Fixed-shift softmax exp2(sc).
__global__ __launch_bounds__(512, 4) void attn_kernel(
    const unsigned short* __restrict__ qb,
    const unsigned short* __restrict__ kb,
    const unsigned short* __restrict__ vt,
    unsigned short* __restrict__ attnb)
{
    __shared__ unsigned short Klds[2][128 * 64];   // 16KB each
    __shared__ unsigned short Vlds[2][64 * 128];   // 16KB each (row=d, 128 s-cols)
    __shared__ unsigned short Plds[8][16 * 64];    // per-wave 2KB; total 80KB

    const int bh = blockIdx.y;
    const int x = blockIdx.x;
    const int qt = (bh < 16) ? (15 - x) : x;      // pair long+short across halves

    const int lane = threadIdx.x & 63;
    const int w = threadIdx.x >> 6;               // 0..7
    const int lg = lane >> 4, ll = lane & 15;
    const int r8 = lane >> 3, ch = (lane & 7) ^ r8;
    const int r4 = lane >> 4, c16 = lane & 15;    // V-stage decomposition

    const unsigned short* Q = qb + bh * (S_LEN * 64);
    const unsigned short* K = kb + bh * (S_LEN * 64);
    const unsigned short* V = vt + bh * (64 * S_LEN);
    const int q0 = qt * 128 + w * 16;             // wave q-base

    u16x8 qf0 = *(const u16x8*)(Q + (q0 + ll) * 64 + lg * 8);
    u16x8 qf1 = *(const u16x8*)(Q + (q0 + ll) * 64 + 32 + lg * 8);

    f32x4 o_acc[4] = {};
    float l_part = 0.0f;

    // ---- precomputed LDS byte addresses ----
    const int sw0 = ((0 * 4 + lg) ^ (ll & 7)) * 16;
    const int sw1 = ((1 * 4 + lg) ^ (ll & 7)) * 16;
    // K read (row stride 128B): base + ll*128 + sw ; half1 = +8192 ; f-stride 2048
    const char* kb0p0 = (const char*)&Klds[0][0] + ll * 128 + sw0;
    const char* kb0p1 = (const char*)&Klds[0][0] + ll * 128 + sw1;
    const char* kb1p0 = (const char*)&Klds[1][0] + ll * 128 + sw0;
    const char* kb1p1 = (const char*)&Klds[1][0] + ll * 128 + sw1;
    // V read (row stride 256B): base + ll*256 + sw ; half1 = +128 ; f-stride 4096
    const char* vb0p0 = (const char*)&Vlds[0][0] + ll * 256 + sw0;
    const char* vb0p1 = (const char*)&Vlds[0][0] + ll * 256 + sw1;
    const char* vb1p0 = (const char*)&Vlds[1][0] + ll * 256 + sw0;
    const char* vb1p1 = (const char*)&Vlds[1][0] + ll * 256 + sw1;
    // P write: addr = ((ll*128+lg*8) ^ (E&16)) + ((f*32) ^ (E&96)),  E=(ll&7)<<4
    const int E = (ll & 7) << 4;
    char* pwb = (char*)&Plds[w][0] + (((ll * 128) + lg * 8) ^ (E & 16));
    const int pw_o0 = 0 ^ (E & 96), pw_o1 = 32 ^ (E & 96);
    const int pw_o2 = 64 ^ (E & 96), pw_o3 = 96 ^ (E & 96);
    const char* pr0 = (const char*)&Plds[w][0] + ll * 128 + sw0;
    const char* pr1 = (const char*)&Plds[w][0] + ll * 128 + sw1;
    // staging: K rows [w*16, +16) = 2 gl16; V rows [w*8, +8) = 2 gl16 (4 rows each)
    unsigned short* kd0 = &Klds[0][(w * 16) * 64];
    unsigned short* kd1 = &Klds[1][(w * 16) * 64];
    unsigned short* vd0 = &Vlds[0][(w * 8) * 128];
    unsigned short* vd1 = &Vlds[1][(w * 8) * 128];
    const unsigned short* gk  = K + (w * 16 + r8) * 64 + ch * 8;
    const unsigned short* gva = V + (w * 8 + r4) * S_LEN + ((c16 ^ r4) * 8);
    const unsigned short* gvb = V + (w * 8 + 4 + r4) * S_LEN + ((c16 ^ (4 + r4)) * 8);
    // diagonal thresholds: half0 thr = dthr, half1 thr = dthr - 64
    const int dthr = w * 16 + ll - lg * 4;

    auto stage2 = [&](unsigned short* kd, unsigned short* vd) {
        gl16(gk, kd);
        gl16(gk + 512, kd + 512);      // K rows +8
        gl16(gva, vd);
        gl16(gvb, vd + 512);           // V rows +4
        gk += 128 * 64;                // next 128-KV tile
        gva += 128;
        gvb += 128;
    };

    auto tile_body = [&](const char* kp0, const char* kp1,
                         const char* vp0, const char* vp1, bool masked, int thr) {
        f32x4 sc[4] = {};
        __builtin_amdgcn_s_setprio(1);
        #pragma unroll
        for (int f = 0; f < 4; f++) {
            const u16x8 kfa = *(const u16x8*)(kp0 + f * 2048);
            sc[f] = mfma16(kfa, qf0, sc[f]);
            const u16x8 kfb = *(const u16x8*)(kp1 + f * 2048);
            sc[f] = mfma16(kfb, qf1, sc[f]);
        }
        __builtin_amdgcn_s_setprio(0);
        if (masked) {
            #pragma unroll
            for (int f = 0; f < 4; f++)
                #pragma unroll
                for (int r = 0; r < 4; r++)
                    if (f * 16 + r > thr) sc[f][r] = -1.0e9f;
        }
        float ts = 0.0f;
        #pragma unroll
        for (int f = 0; f < 4; f++)
            #pragma unroll
            for (int r = 0; r < 4; r++) {
                const float p = __builtin_amdgcn_exp2f(sc[f][r]);
                sc[f][r] = p;
                ts += p;
            }
        l_part += ts;
        *(unsigned long long*)(pwb + pw_o0) =
            (unsigned long long)cvtpk(sc[0][0], sc[0][1]) | ((unsigned long long)cvtpk(sc[0][2], sc[0][3]) << 32);
        *(unsigned long long*)(pwb + pw_o1) =
            (unsigned long long)cvtpk(sc[1][0], sc[1][1]) | ((unsigned long long)cvtpk(sc[1][2], sc[1][3]) << 32);
        *(unsigned long long*)(pwb + pw_o2) =
            (unsigned long long)cvtpk(sc[2][0], sc[2][1]) | ((unsigned long long)cvtpk(sc[2][2], sc[2][3]) << 32);
        *(unsigned long long*)(pwb + pw_o3) =
            (unsigned long long)cvtpk(sc[3][0], sc[3][1]) | ((unsigned long long)cvtpk(sc[3][2], sc[3][3]) << 32);
        const u16x8 pf0 = *(const u16x8*)pr0;
        const u16x8 pf1 = *(const u16x8*)pr1;
        __builtin_amdgcn_s_setprio(1);
        #pragma unroll
        for (int f = 0; f < 4; f++) {
            o_acc[f] = mfma16(pf0, *(const u16x8*)(vp0 + f * 4096), o_acc[f]);
            o_acc[f] = mfma16(pf1, *(const u16x8*)(vp1 + f * 4096), o_acc[f]);
        }
        __builtin_amdgcn_s_setprio(0);
    };

    // body over one 128-KV buffer: two 64-halves
    auto body128_full = [&](const char* kp0, const char* kp1,
                            const char* vp0, const char* vp1) {
        tile_body(kp0, kp1, vp0, vp1, false, 0);
        tile_body(kp0 + 8192, kp1 + 8192, vp0 + 128, vp1 + 128, false, 0);
    };
    auto body128_diag = [&](const char* kp0, const char* kp1,
                            const char* vp0, const char* vp1) {
        tile_body(kp0, kp1, vp0, vp1, true, dthr);
        if (w >= 4)   // waves 0-3: second half fully masked
            tile_body(kp0 + 8192, kp1 + 8192, vp0 + 128, vp1 + 128, true, dthr - 64);
    };

    stage2(kd0, vd0);                      // tile 0 -> buf0
    __syncthreads();                       // buf0 ready

    int p = 0;
    while (p + 2 <= qt) {                  // two full 128-tiles
        stage2(kd1, vd1);                  // tile p+1 -> buf1
        body128_full(kb0p0, kb0p1, vb0p0, vb0p1);
        __syncthreads();                   // drains stage(p+1); buf1 ready
        stage2(kd0, vd0);                  // tile p+2 -> buf0
        body128_full(kb1p0, kb1p1, vb1p0, vb1p1);
        __syncthreads();                   // drains stage(p+2); buf0 ready
        p += 2;
    }
    if (p < qt) {                          // one full tile (p, buf0) + diag (buf1)
        stage2(kd1, vd1);                  // tile qt -> buf1
        body128_full(kb0p0, kb0p1, vb0p0, vb0p1);
        __syncthreads();
        body128_diag(kb1p0, kb1p1, vb1p0, vb1p1);
    } else {                               // diag in buf0
        body128_diag(kb0p0, kb0p1, vb0p0, vb0p1);
    }

    // one-time l reduction: lane (lg,ll) holds partial over its kv-subset of q=ll
    l_part += __shfl_xor(l_part, 16);
    l_part += __shfl_xor(l_part, 32);

    const int bb = bh >> 4, h = bh & 15;
    float lr0 = 1.0f / __shfl(l_part, lg * 4 + 0);
    float lr1 = 1.0f / __shfl(l_part, lg * 4 + 1);
    float lr2 = 1.0f / __shfl(l_part, lg * 4 + 2);
    float lr3 = 1.0f / __shfl(l_part, lg * 4 + 3);
    #pragma unroll
    for (int f = 0; f < 4; f++) {
        const int colbase = h * 64 + f * 16 + ll;
        attnb[(bb * S_LEN + q0 + lg * 4 + 0) * DMODEL + colbase] = f2bf(o_acc[f][0] * lr0);
        attnb[(bb * S_LEN + q0 + lg * 4 + 1) * DMODEL + colbase] = f2bf(o_acc[f][1] * lr1);
        attnb[(bb * S_LEN + q0 + lg * 4 + 2) * DMODEL + colbase] = f2bf(o_acc[f][2] * lr2);
        attnb[(bb * S_LEN + q0 + lg * 4 + 3) * DMODEL + colbase] = f2bf(o_acc[f][3] * lr3);
    }
}

// ---------------------------------------------------------------- out GEMM
// out = attn @ Wo^T + X. 3-buffer counted-vmcnt pipeline, 2-wave 128x64.
__global__ __launch_bounds__(128) void gemm_out(
    const unsigned short* __restrict__ Abf,
    const unsigned short* __restrict__ Wbf,
    const float* __restrict__ X,
    float* __restrict__ out)
{
    const unsigned short* __restrict__ W = Wbf + (3u << 20);
    __shared__ unsigned short L[3][192 * 64];   // 72KB
    const int t = threadIdx.x;
    const int lane = t & 63;
    const int w = t >> 6;
    const int m0 = blockIdx.x * 128;
    const int n0 = blockIdx.y * 64;
    const int ll = lane & 15, lg = lane >> 4;
    const int r8 = lane >> 3, ch = (lane & 7) ^ r8;

    f32x4 acc[4][4] = {};

    const unsigned short* gA[8];
    const unsigned short* gB[4];
    #pragma unroll
    for (int i = 0; i < 8; i++) gA[i] = Abf + (m0 + w * 64 + i * 8 + r8) * 1024 + ch * 8;
    #pragma unroll
    for (int i = 0; i < 4; i++) gB[i] = W + (n0 + w * 32 + i * 8 + r8) * 1024 + ch * 8;

    const int sw0 = ((0 * 4 + lg) ^ (ll & 7)) * 16;
    const int sw1 = ((1 * 4 + lg) ^ (ll & 7)) * 16;

    auto stage = [&](unsigned short* Lb) {
        unsigned short* const dA = Lb + (w * 64) * 64;
        unsigned short* const dB = Lb + 128 * 64 + (w * 32) * 64;
        #pragma unroll
        for (int i = 0; i < 8; i++) { gl16(gA[i], dA + i * 8 * 64); gA[i] += 64; }
        #pragma unroll
        for (int i = 0; i < 4; i++) { gl16(gB[i], dB + i * 8 * 64); gB[i] += 64; }
    };
    auto compute = [&](const unsigned short* Lb) {
        const char* const pA0 = (const char*)Lb + (w * 64 + ll) * 128 + sw0;
        const char* const pA1 = (const char*)Lb + (w * 64 + ll) * 128 + sw1;
        const char* const pB0 = (const char*)Lb + 16384 + ll * 128 + sw0;
        const char* const pB1 = (const char*)Lb + 16384 + ll * 128 + sw1;
        u16x8 af[4], bfv[4];
        #pragma unroll
        for (int m = 0; m < 4; m++) af[m] = *(const u16x8*)(pA0 + m * 2048);
        #pragma unroll
        for (int n = 0; n < 4; n++) bfv[n] = *(const u16x8*)(pB0 + n * 2048);
        __builtin_amdgcn_s_setprio(1);
        #pragma unroll
        for (int m = 0; m < 4; m++)
            #pragma unroll
            for (int n = 0; n < 4; n++)
                acc[m][n] = mfma16(af[m], bfv[n], acc[m][n]);
        __builtin_amdgcn_s_setprio(0);
        #pragma unroll
        for (int m = 0; m < 4; m++) af[m] = *(const u16x8*)(pA1 + m * 2048);
        #pragma unroll
        for (int n = 0; n < 4; n++) bfv[n] = *(const u16x8*)(pB1 + n * 2048);
        __builtin_amdgcn_s_setprio(1);
        #pragma unroll
        for (int m = 0; m < 4; m++)
            #pragma unroll
            for (int n = 0; n < 4; n++)
                acc[m][n] = mfma16(af[m], bfv[n], acc[m][n]);
        __builtin_amdgcn_s_setprio(0);
    };

    stage(L[0]);
    stage(L[1]);
    PIPE_BAR_12();
    for (int tt = 0; tt < 4; tt++) {
        stage(L[2]); compute(L[0]); PIPE_BAR_12();
        stage(L[0]); compute(L[1]); PIPE_BAR_12();
        stage(L[1]); compute(L[2]); PIPE_BAR_12();
    }
    stage(L[2]); compute(L[0]); PIPE_BAR_12();
    stage(L[0]); compute(L[1]); PIPE_BAR_12();
    compute(L[2]); PIPE_BAR_0();
    compute(L[0]);

    #pragma unroll
    for (int m = 0; m < 4; m++)
        #pragma unroll
        for (int n = 0; n < 4; n++)
            #pragma unroll
            for (int r = 0; r < 4; r++) {
                const int row = m0 + w * 64 + m * 16 + lg * 4 + r;
                const int col = n0 + n * 16 + ll;
                out[row * 1024 + col] = acc[m][n][r] + X[row * 1024 + col];
            }
}

// ---------------------------------------------------------------- launch
extern "C" void kernel_launch(void* const* d_in, const int* in_sizes, int n_in,
                              void* d_out, int out_size, void* d_ws, size_t ws_size,
                              hipStream_t stream) {
    const float* X  = (const float*)d_in[0];
    const float* Wq = (const float*)d_in[1];
    const float* Wk = (const float*)d_in[2];
    const float* Wv = (const float*)d_in[3];
    const float* Wo = (const float*)d_in[4];
    float* out = (float*)d_out;

    char* ws = (char*)d_ws;
    float*          pos  = (float*)(ws);                                   // 512 KB
    unsigned short* Xbf  = (unsigned short*)(ws + (512u << 10));           // 8 MB (reused as attb)
    unsigned short* Wbf  = (unsigned short*)(ws + (512u << 10) + (8u  << 20));  // 8 MB (4 stacked)
    unsigned short* qb   = (unsigned short*)(ws + (512u << 10) + (16u << 20));
    unsigned short* kb   = (unsigned short*)(ws + (512u << 10) + (24u << 20));
    unsigned short* vt   = (unsigned short*)(ws + (512u << 10) + (32u << 20));
    unsigned short* attb = Xbf;   // Xbf dead after gemm_qkv; reuse for attn output

    cvt5<<<dim3(4608), dim3(256), 0, stream>>>(X, Wq, Wk, Wv, Wo, Xbf, Wbf, pos);
    gemm_qkv<<<dim3(16, 12), dim3(512), 0, stream>>>(Xbf, Wbf, pos, qb, kb, vt);
    attn_kernel<<<dim3(16, 32), dim3(512), 0, stream>>>(qb, kb, vt, attb);
    gemm_out<<<dim3(32, 16), dim3(128), 0, stream>>>(attb, Wbf, X, out);
}

// Round 15
// 95.422 us; speedup vs baseline: 1.1216x; 1.0039x over previous
//
#include <hip/hip_runtime.h>
#include <hip/hip_bf16.h>
#include <math.h>

#define S_LEN 2048
#define DMODEL 1024
#define NHEADS 16
#define DHEAD 64
#define NBATCH 2
#define MROWS (NBATCH * S_LEN)   // 4096

typedef float f32x4 __attribute__((ext_vector_type(4)));
typedef unsigned short u16x8 __attribute__((ext_vector_type(8)));
typedef __bf16 bf16x8 __attribute__((ext_vector_type(8)));

__device__ __forceinline__ f32x4 mfma16(u16x8 a, u16x8 b, f32x4 c) {
    return __builtin_amdgcn_mfma_f32_16x16x32_bf16(
        __builtin_bit_cast(bf16x8, a), __builtin_bit_cast(bf16x8, b), c, 0, 0, 0);
}

// f32 -> bf16 round-to-nearest-even
__device__ __forceinline__ unsigned short f2bf(float f) {
    unsigned int u = __builtin_bit_cast(unsigned int, f);
    u += 0x7FFFu + ((u >> 16) & 1u);
    return (unsigned short)(u >> 16);
}

// packed f32x2 -> bf16x2 (RTNE), single HW instruction; low16 = lo
__device__ __forceinline__ unsigned int cvtpk(float lo, float hi) {
    unsigned int r;
    asm("v_cvt_pk_bf16_f32 %0, %1, %2" : "=v"(r) : "v"(lo), "v"(hi));
    return r;
}

// async global->LDS, 16B per lane; lds dest = wave-uniform base + lane*16
__device__ __forceinline__ void gl16(const void* g, void* l) {
    __builtin_amdgcn_global_load_lds(
        (const __attribute__((address_space(1))) unsigned int*)g,
        (__attribute__((address_space(3))) unsigned int*)l, 16, 0, 0);
}

// counted-vmcnt publishing barrier (sched_barrier fences both sides)
#define VMB(N) do { \
    asm volatile("s_waitcnt vmcnt(" #N ")" ::: "memory"); \
    __builtin_amdgcn_sched_barrier(0); \
    __builtin_amdgcn_s_barrier(); \
    __builtin_amdgcn_sched_barrier(0); } while (0)
#define PIPE_BAR_12() do { \
    asm volatile("s_waitcnt vmcnt(12)" ::: "memory"); \
    __builtin_amdgcn_sched_barrier(0); \
    __builtin_amdgcn_s_barrier(); \
    __builtin_amdgcn_sched_barrier(0); } while (0)
#define PIPE_BAR_0() do { \
    asm volatile("s_waitcnt vmcnt(0)" ::: "memory"); \
    __builtin_amdgcn_sched_barrier(0); \
    __builtin_amdgcn_s_barrier(); \
    __builtin_amdgcn_sched_barrier(0); } while (0)

// ---------------------------------------------------------------- cvt + pos
// blocks 0..2047: X. 2048..4095: Wq,Wk,Wv,Wo. 4096..4607: pos table.
__global__ __launch_bounds__(256) void cvt5(
    const float* __restrict__ X, const float* __restrict__ Wq,
    const float* __restrict__ Wk, const float* __restrict__ Wv,
    const float* __restrict__ Wo,
    unsigned short* __restrict__ Xbf, unsigned short* __restrict__ Wbf,
    float* __restrict__ pos)
{
    int b = blockIdx.x;
    if (b >= 4096) {
        int i = (b - 4096) * 256 + threadIdx.x;
        int s = i >> 6, d = i & 63;
        float theta = powf(10000.0f, (2.0f * (float)d) / 64.0f);
        float x = (float)s / theta;
        float v = (d & 1) ? cosf(x) : sinf(x);
        pos[i] = (s == 0) ? 0.0f : v;
        return;
    }
    const float* s; unsigned short* d; int t;
    if (b < 2048) { s = X; d = Xbf; t = b * 256 + threadIdx.x; }
    else {
        int z = (b - 2048) >> 9, bb = (b - 2048) & 511;
        s = (z == 0) ? Wq : (z == 1) ? Wk : (z == 2) ? Wv : Wo;
        d = Wbf + (z << 20);
        t = bb * 256 + threadIdx.x;
    }
    float4 a = *((const float4*)s + t * 2);
    float4 c = *((const float4*)s + t * 2 + 1);
    u16x8 o;
    o[0] = f2bf(a.x); o[1] = f2bf(a.y); o[2] = f2bf(a.z); o[3] = f2bf(a.w);
    o[4] = f2bf(c.x); o[5] = f2bf(c.y); o[6] = f2bf(c.z); o[7] = f2bf(c.w);
    *((u16x8*)d + t) = o;
}

// ---------------------------------------------------------------- QKV GEMM (bf16 in)
// 256x256 tile, BK=64, 512 thr (8 waves, 2Mx4N), grid (16,12). 2 x 64KB LDS.
// 4-phase K-tile with COUNTED waits (never 0 in main loop):
//  stage order per tile (2 gl16/thread/phase): B[0-127], B[128-255],
//  A[0-63]+A[128-191], A[64-127]+A[192-255].
//  Quads 0-1 read the first A pair; quads 2-3 the second.
//  Boundary wait vmcnt(2): oldest 6 of 8 outstanding = next tile's B + first-A.
//  Mid-tile wait vmcnt(6) before quad2: oldest 2 = this tile's last A pair.
__global__ __launch_bounds__(512) void gemm_qkv(
    const unsigned short* __restrict__ Xbf, const unsigned short* __restrict__ Wbf,
    const float* __restrict__ pos,
    unsigned short* __restrict__ qb, unsigned short* __restrict__ kb,
    unsigned short* __restrict__ vt)
{
    const int y = blockIdx.y;
    const int z = y >> 2;
    const unsigned short* __restrict__ W = Wbf + (z << 20);
    __shared__ unsigned short L[2][32768];   // 64KB per buffer: A @0, B @elem 16384
    const int t = threadIdx.x;               // 0..511
    const int lane = t & 63;
    const int w = t >> 6;                    // 0..7
    const int wm = w >> 2, wn = w & 3;
    const int m0 = blockIdx.x * 256;
    const int nb = (y & 3) * 256;
    const int ll = lane & 15, lg = lane >> 4;
    const int tr = t >> 3;                   // 0..63: row within each 64-row group
    const int ch = (t & 7) ^ (tr & 7);       // pre-swizzled source chunk

    f32x4 acc[8][4] = {};

    // running global stage pointers (advance 64 elems per K-tile)
    const unsigned short* gA[4];
    const unsigned short* gB[4];
    #pragma unroll
    for (int i = 0; i < 4; i++) {
        gA[i] = Xbf + (m0 + i * 64 + tr) * 1024 + ch * 8;
        gB[i] = W + (nb + i * 64 + tr) * 1024 + ch * 8;
    }

    const int sw0 = ((0 * 4 + lg) ^ (ll & 7)) * 16;
    const int sw1 = ((1 * 4 + lg) ^ (ll & 7)) * 16;
    const int aBase = (wm * 128 + ll) * 128;            // byte; + q*4096 + sw
    const int bBase = 32768 + (wn * 64 + ll) * 128;     // byte; + nf*2048 + sw
    const int wdst = w * 8 * 64;                        // element; wave's stage rows

    // stage pairs (2 gl16/thread each); group i lives at elem i*4096 (A) /
    // 16384 + i*4096 (B)
    auto stB01 = [&](unsigned short* Ln) {
        gl16(gB[0], Ln + 16384 + wdst);          gB[0] += 64;
        gl16(gB[1], Ln + 16384 + 4096 + wdst);   gB[1] += 64;
    };
    auto stB23 = [&](unsigned short* Ln) {
        gl16(gB[2], Ln + 16384 + 8192 + wdst);   gB[2] += 64;
        gl16(gB[3], Ln + 16384 + 12288 + wdst);  gB[3] += 64;
    };
    auto stA02 = [&](unsigned short* Ln) {       // A rows 0-63, 128-191
        gl16(gA[0], Ln + wdst);                  gA[0] += 64;
        gl16(gA[2], Ln + 8192 + wdst);           gA[2] += 64;
    };
    auto stA13 = [&](unsigned short* Ln) {       // A rows 64-127, 192-255
        gl16(gA[1], Ln + 4096 + wdst);           gA[1] += 64;
        gl16(gA[3], Ln + 12288 + wdst);          gA[3] += 64;
    };

    u16x8 bf[4][2];
    auto loadB = [&](const char* bB) {
        #pragma unroll
        for (int nf = 0; nf < 4; nf++) {
            const char* p = bB + bBase + nf * 2048;
            bf[nf][0] = *(const u16x8*)(p + sw0);
            bf[nf][1] = *(const u16x8*)(p + sw1);
        }
    };
    auto quad = [&](int q, const char* bA) {
        const char* pa = bA + aBase + q * 4096;
        u16x8 a00 = *(const u16x8*)(pa + sw0);
        u16x8 a01 = *(const u16x8*)(pa + sw1);
        u16x8 a10 = *(const u16x8*)(pa + 2048 + sw0);
        u16x8 a11 = *(const u16x8*)(pa + 2048 + sw1);
        __builtin_amdgcn_s_setprio(1);
        #pragma unroll
        for (int nf = 0; nf < 4; nf++) {
            acc[q * 2 + 0][nf] = mfma16(a00, bf[nf][0], acc[q * 2 + 0][nf]);
            acc[q * 2 + 1][nf] = mfma16(a10, bf[nf][0], acc[q * 2 + 1][nf]);
        }
        #pragma unroll
        for (int nf = 0; nf < 4; nf++) {
            acc[q * 2 + 0][nf] = mfma16(a01, bf[nf][1], acc[q * 2 + 0][nf]);
            acc[q * 2 + 1][nf] = mfma16(a11, bf[nf][1], acc[q * 2 + 1][nf]);
        }
        __builtin_amdgcn_s_setprio(0);
    };

    // prologue: stage tile 0 in canonical order; boundary wait (A13 in flight)
    stB01(L[0]); stB23(L[0]); stA02(L[0]); stA13(L[0]);
    VMB(2);

    // tiles 0..14: compute buf tt&1, stage tile tt+1 into other buf
    #pragma unroll 1
    for (int tt = 0; tt < 15; tt++) {
        const char* bA = (const char*)L[tt & 1];
        unsigned short* Ln = L[(tt + 1) & 1];
        stB01(Ln);                    // P1
        loadB(bA);
        quad(0, bA);
        __builtin_amdgcn_s_barrier();
        stB23(Ln);                    // P2
        quad(1, bA);
        __builtin_amdgcn_s_barrier();
        stA02(Ln);                    // P3
        VMB(6);                       // publishes this tile's A13
        quad(2, bA);
        __builtin_amdgcn_s_barrier();
        stA13(Ln);                    // P4
        quad(3, bA);
        VMB(2);                       // boundary: next tile's B+A02 published
    }
    // tail tile 15 (no staging; only its A13 may be outstanding at mid-wait)
    {
        const char* bA = (const char*)L[1];
        loadB(bA);
        quad(0, bA);
        __builtin_amdgcn_s_barrier();
        quad(1, bA);
        VMB(0);                       // publish A13 of tile 15
        quad(2, bA);
        quad(3, bA);
    }

    if (z == 2) {
        // V^T: r=0..3 are s-consecutive -> one packed u64 store per (mf,nf)
        #pragma unroll
        for (int mf = 0; mf < 8; mf++) {
            const int row0 = m0 + wm * 128 + mf * 16 + lg * 4;
            const int b = row0 >> 11, s0 = row0 & 2047;
            #pragma unroll
            for (int nf = 0; nf < 4; nf++) {
                const int c = nb + wn * 64 + nf * 16 + ll;   // h*64 + d
                const int h = c >> 6, d = c & 63;
                unsigned long long pk =
                    (unsigned long long)cvtpk(acc[mf][nf][0], acc[mf][nf][1]) |
                    ((unsigned long long)cvtpk(acc[mf][nf][2], acc[mf][nf][3]) << 32);
                *(unsigned long long*)&vt[(((b * NHEADS + h) * 64) + d) * S_LEN + s0] = pk;
            }
        }
    } else {
        unsigned short* const dst = (z == 0) ? qb : kb;
        #pragma unroll
        for (int mf = 0; mf < 8; mf++) {
            #pragma unroll
            for (int nf = 0; nf < 4; nf++) {
                #pragma unroll
                for (int r = 0; r < 4; r++) {
                    const int row = m0 + wm * 128 + mf * 16 + lg * 4 + r;
                    const int c = nb + wn * 64 + nf * 16 + ll;
                    const int b = row >> 11, s = row & 2047;
                    const int h = c >> 6, d = c & 63;
                    float v = acc[mf][nf][r] + pos[s * 64 + d];
                    // Q: fold 1/sqrt(d_k) * log2(e) so softmax can use exp2
                    if (z == 0) v *= 0.1803368801111244f;
                    dst[(((b * NHEADS + h) * S_LEN) + s) * 64 + d] = f2bf(v);
                }
            }
        }
    }
}

// ---------------------------------------------------------------- attention
// grid (16 qt, 32 bh), 8 waves x 512 thr, QBLK=128 (wave owns 16 q-rows).
// KVBLK=128: one barrier interval covers 128 KV rows (two 64-halves run
// back-to-back). K[2][128x64] + V^T[2][64x128] double-buffered (64KB) +
// per-wave P (16KB) = 80KB. Diagonal 128-tile peeled; waves 0-3 skip its
// fully-masked second half. Fixed-shift softmax exp2(sc).
__global__ __launch_bounds__(512, 4) void attn_kernel(
    const unsigned short* __restrict__ qb,
    const unsigned short* __restrict__ kb,
    const unsigned short* __restrict__ vt,
    unsigned short* __restrict__ attnb)
{
    __shared__ unsigned short Klds[2][128 * 64];   // 16KB each
    __shared__ unsigned short Vlds[2][64 * 128];   // 16KB each (row=d, 128 s-cols)
    __shared__ unsigned short Plds[8][16 * 64];    // per-wave 2KB; total 80KB

    const int bh = blockIdx.y;
    const int x = blockIdx.x;
    const int qt = (bh < 16) ? (15 - x) : x;      // pair long+short across halves

    const int lane = threadIdx.x & 63;
    const int w = threadIdx.x >> 6;               // 0..7
    const int lg = lane >> 4, ll = lane & 15;
    const int r8 = lane >> 3, ch = (lane & 7) ^ r8;
    const int r4 = lane >> 4, c16 = lane & 15;    // V-stage decomposition

    const unsigned short* Q = qb + bh * (S_LEN * 64);
    const unsigned short* K = kb + bh * (S_LEN * 64);
    const unsigned short* V = vt + bh * (64 * S_LEN);
    const int q0 = qt * 128 + w * 16;             // wave q-base

    u16x8 qf0 = *(const u16x8*)(Q + (q0 + ll) * 64 + lg * 8);
    u16x8 qf1 = *(const u16x8*)(Q + (q0 + ll) * 64 + 32 + lg * 8);

    f32x4 o_acc[4] = {};
    float l_part = 0.0f;

    // ---- precomputed LDS byte addresses ----
    const int sw0 = ((0 * 4 + lg) ^ (ll & 7)) * 16;
    const int sw1 = ((1 * 4 + lg) ^ (ll & 7)) * 16;
    // K read (row stride 128B): base + ll*128 + sw ; half1 = +8192 ; f-stride 2048
    const char* kb0p0 = (const char*)&Klds[0][0] + ll * 128 + sw0;
    const char* kb0p1 = (const char*)&Klds[0][0] + ll * 128 + sw1;
    const char* kb1p0 = (const char*)&Klds[1][0] + ll * 128 + sw0;
    const char* kb1p1 = (const char*)&Klds[1][0] + ll * 128 + sw1;
    // V read (row stride 256B): base + ll*256 + sw ; half1 = +128 ; f-stride 4096
    const char* vb0p0 = (const char*)&Vlds[0][0] + ll * 256 + sw0;
    const char* vb0p1 = (const char*)&Vlds[0][0] + ll * 256 + sw1;
    const char* vb1p0 = (const char*)&Vlds[1][0] + ll * 256 + sw0;
    const char* vb1p1 = (const char*)&Vlds[1][0] + ll * 256 + sw1;
    // P write: addr = ((ll*128+lg*8) ^ (E&16)) + ((f*32) ^ (E&96)),  E=(ll&7)<<4
    const int E = (ll & 7) << 4;
    char* pwb = (char*)&Plds[w][0] + (((ll * 128) + lg * 8) ^ (E & 16));
    const int pw_o0 = 0 ^ (E & 96), pw_o1 = 32 ^ (E & 96);
    const int pw_o2 = 64 ^ (E & 96), pw_o3 = 96 ^ (E & 96);
    const char* pr0 = (const char*)&Plds[w][0] + ll * 128 + sw0;
    const char* pr1 = (const char*)&Plds[w][0] + ll * 128 + sw1;
    // staging: K rows [w*16, +16) = 2 gl16; V rows [w*8, +8) = 2 gl16 (4 rows each)
    unsigned short* kd0 = &Klds[0][(w * 16) * 64];
    unsigned short* kd1 = &Klds[1][(w * 16) * 64];
    unsigned short* vd0 = &Vlds[0][(w * 8) * 128];
    unsigned short* vd1 = &Vlds[1][(w * 8) * 128];
    const unsigned short* gk  = K + (w * 16 + r8) * 64 + ch * 8;
    const unsigned short* gva = V + (w * 8 + r4) * S_LEN + ((c16 ^ r4) * 8);
    const unsigned short* gvb = V + (w * 8 + 4 + r4) * S_LEN + ((c16 ^ (4 + r4)) * 8);
    // diagonal thresholds: half0 thr = dthr, half1 thr = dthr - 64
    const int dthr = w * 16 + ll - lg * 4;

    auto stage2 = [&](unsigned short* kd, unsigned short* vd) {
        gl16(gk, kd);
        gl16(gk + 512, kd + 512);      // K rows +8
        gl16(gva, vd);
        gl16(gvb, vd + 512);           // V rows +4
        gk += 128 * 64;                // next 128-KV tile
        gva += 128;
        gvb += 128;
    };

    auto tile_body = [&](const char* kp0, const char* kp1,
                         const char* vp0, const char* vp1, bool masked, int thr) {
        f32x4 sc[4] = {};
        __builtin_amdgcn_s_setprio(1);
        #pragma unroll
        for (int f = 0; f < 4; f++) {
            const u16x8 kfa = *(const u16x8*)(kp0 + f * 2048);
            sc[f] = mfma16(kfa, qf0, sc[f]);
            const u16x8 kfb = *(const u16x8*)(kp1 + f * 2048);
            sc[f] = mfma16(kfb, qf1, sc[f]);
        }
        __builtin_amdgcn_s_setprio(0);
        if (masked) {
            #pragma unroll
            for (int f = 0; f < 4; f++)
                #pragma unroll
                for (int r = 0; r < 4; r++)
                    if (f * 16 + r > thr) sc[f][r] = -1.0e9f;
        }
        float ts = 0.0f;
        #pragma unroll
        for (int f = 0; f < 4; f++)
            #pragma unroll
            for (int r = 0; r < 4; r++) {
                const float p = __builtin_amdgcn_exp2f(sc[f][r]);
                sc[f][r] = p;
                ts += p;
            }
        l_part += ts;
        *(unsigned long long*)(pwb + pw_o0) =
            (unsigned long long)cvtpk(sc[0][0], sc[0][1]) | ((unsigned long long)cvtpk(sc[0][2], sc[0][3]) << 32);
        *(unsigned long long*)(pwb + pw_o1) =
            (unsigned long long)cvtpk(sc[1][0], sc[1][1]) | ((unsigned long long)cvtpk(sc[1][2], sc[1][3]) << 32);
        *(unsigned long long*)(pwb + pw_o2) =
            (unsigned long long)cvtpk(sc[2][0], sc[2][1]) | ((unsigned long long)cvtpk(sc[2][2], sc[2][3]) << 32);
        *(unsigned long long*)(pwb + pw_o3) =
            (unsigned long long)cvtpk(sc[3][0], sc[3][1]) | ((unsigned long long)cvtpk(sc[3][2], sc[3][3]) << 32);
        const u16x8 pf0 = *(const u16x8*)pr0;
        const u16x8 pf1 = *(const u16x8*)pr1;
        __builtin_amdgcn_s_setprio(1);
        #pragma unroll
        for (int f = 0; f < 4; f++) {
            o_acc[f] = mfma16(pf0, *(const u16x8*)(vp0 + f * 4096), o_acc[f]);
            o_acc[f] = mfma16(pf1, *(const u16x8*)(vp1 + f * 4096), o_acc[f]);
        }
        __builtin_amdgcn_s_setprio(0);
    };

    // body over one 128-KV buffer: two 64-halves
    auto body128_full = [&](const char* kp0, const char* kp1,
                            const char* vp0, const char* vp1) {
        tile_body(kp0, kp1, vp0, vp1, false, 0);
        tile_body(kp0 + 8192, kp1 + 8192, vp0 + 128, vp1 + 128, false, 0);
    };
    auto body128_diag = [&](const char* kp0, const char* kp1,
                            const char* vp0, const char* vp1) {
        tile_body(kp0, kp1, vp0, vp1, true, dthr);
        if (w >= 4)   // waves 0-3: second half fully masked
            tile_body(kp0 + 8192, kp1 + 8192, vp0 + 128, vp1 + 128, true, dthr - 64);
    };

    stage2(kd0, vd0);                      // tile 0 -> buf0
    __syncthreads();                       // buf0 ready

    int p = 0;
    while (p + 2 <= qt) {                  // two full 128-tiles
        stage2(kd1, vd1);                  // tile p+1 -> buf1
        body128_full(kb0p0, kb0p1, vb0p0, vb0p1);
        __syncthreads();                   // drains stage(p+1); buf1 ready
        stage2(kd0, vd0);                  // tile p+2 -> buf0
        body128_full(kb1p0, kb1p1, vb1p0, vb1p1);
        __syncthreads();                   // drains stage(p+2); buf0 ready
        p += 2;
    }
    if (p < qt) {                          // one full tile (p, buf0) + diag (buf1)
        stage2(kd1, vd1);                  // tile qt -> buf1
        body128_full(kb0p0, kb0p1, vb0p0, vb0p1);
        __syncthreads();
        body128_diag(kb1p0, kb1p1, vb1p0, vb1p1);
    } else {                               // diag in buf0
        body128_diag(kb0p0, kb0p1, vb0p0, vb0p1);
    }

    // one-time l reduction: lane (lg,ll) holds partial over its kv-subset of q=ll
    l_part += __shfl_xor(l_part, 16);
    l_part += __shfl_xor(l_part, 32);

    const int bb = bh >> 4, h = bh & 15;
    float lr0 = 1.0f / __shfl(l_part, lg * 4 + 0);
    float lr1 = 1.0f / __shfl(l_part, lg * 4 + 1);
    float lr2 = 1.0f / __shfl(l_part, lg * 4 + 2);
    float lr3 = 1.0f / __shfl(l_part, lg * 4 + 3);
    #pragma unroll
    for (int f = 0; f < 4; f++) {
        const int colbase = h * 64 + f * 16 + ll;
        attnb[(bb * S_LEN + q0 + lg * 4 + 0) * DMODEL + colbase] = f2bf(o_acc[f][0] * lr0);
        attnb[(bb * S_LEN + q0 + lg * 4 + 1) * DMODEL + colbase] = f2bf(o_acc[f][1] * lr1);
        attnb[(bb * S_LEN + q0 + lg * 4 + 2) * DMODEL + colbase] = f2bf(o_acc[f][2] * lr2);
        attnb[(bb * S_LEN + q0 + lg * 4 + 3) * DMODEL + colbase] = f2bf(o_acc[f][3] * lr3);
    }
}

// ---------------------------------------------------------------- out GEMM
// out = attn @ Wo^T + X. 3-buffer counted-vmcnt pipeline, 2-wave 128x64.
__global__ __launch_bounds__(128) void gemm_out(
    const unsigned short* __restrict__ Abf,
    const unsigned short* __restrict__ Wbf,
    const float* __restrict__ X,
    float* __restrict__ out)
{
    const unsigned short* __restrict__ W = Wbf + (3u << 20);
    __shared__ unsigned short L[3][192 * 64];   // 72KB
    const int t = threadIdx.x;
    const int lane = t & 63;
    const int w = t >> 6;
    const int m0 = blockIdx.x * 128;
    const int n0 = blockIdx.y * 64;
    const int ll = lane & 15, lg = lane >> 4;
    const int r8 = lane >> 3, ch = (lane & 7) ^ r8;

    f32x4 acc[4][4] = {};

    const unsigned short* gA[8];
    const unsigned short* gB[4];
    #pragma unroll
    for (int i = 0; i < 8; i++) gA[i] = Abf + (m0 + w * 64 + i * 8 + r8) * 1024 + ch * 8;
    #pragma unroll
    for (int i = 0; i < 4; i++) gB[i] = W + (n0 + w * 32 + i * 8 + r8) * 1024 + ch * 8;

    const int sw0 = ((0 * 4 + lg) ^ (ll & 7)) * 16;
    const int sw1 = ((1 * 4 + lg) ^ (ll & 7)) * 16;

    auto stage = [&](unsigned short* Lb) {
        unsigned short* const dA = Lb + (w * 64) * 64;
        unsigned short* const dB = Lb + 128 * 64 + (w * 32) * 64;
        #pragma unroll
        for (int i = 0; i < 8; i++) { gl16(gA[i], dA + i * 8 * 64); gA[i] += 64; }
        #pragma unroll
        for (int i = 0; i < 4; i++) { gl16(gB[i], dB + i * 8 * 64); gB[i] += 64; }
    };
    auto compute = [&](const unsigned short* Lb) {
        const char* const pA0 = (const char*)Lb + (w * 64 + ll) * 128 + sw0;
        const char* const pA1 = (const char*)Lb + (w * 64 + ll) * 128 + sw1;
        const char* const pB0 = (const char*)Lb + 16384 + ll * 128 + sw0;
        const char* const pB1 = (const char*)Lb + 16384 + ll * 128 + sw1;
        u16x8 af[4], bfv[4];
        #pragma unroll
        for (int m = 0; m < 4; m++) af[m] = *(const u16x8*)(pA0 + m * 2048);
        #pragma unroll
        for (int n = 0; n < 4; n++) bfv[n] = *(const u16x8*)(pB0 + n * 2048);
        __builtin_amdgcn_s_setprio(1);
        #pragma unroll
        for (int m = 0; m < 4; m++)
            #pragma unroll
            for (int n = 0; n < 4; n++)
                acc[m][n] = mfma16(af[m], bfv[n], acc[m][n]);
        __builtin_amdgcn_s_setprio(0);
        #pragma unroll
        for (int m = 0; m < 4; m++) af[m] = *(const u16x8*)(pA1 + m * 2048);
        #pragma unroll
        for (int n = 0; n < 4; n++) bfv[n] = *(const u16x8*)(pB1 + n * 2048);
        __builtin_amdgcn_s_setprio(1);
        #pragma unroll
        for (int m = 0; m < 4; m++)
            #pragma unroll
            for (int n = 0; n < 4; n++)
                acc[m][n] = mfma16(af[m], bfv[n], acc[m][n]);
        __builtin_amdgcn_s_setprio(0);
    };

    stage(L[0]);
    stage(L[1]);
    PIPE_BAR_12();
    for (int tt = 0; tt < 4; tt++) {
        stage(L[2]); compute(L[0]); PIPE_BAR_12();
        stage(L[0]); compute(L[1]); PIPE_BAR_12();
        stage(L[1]); compute(L[2]); PIPE_BAR_12();
    }
    stage(L[2]); compute(L[0]); PIPE_BAR_12();
    stage(L[0]); compute(L[1]); PIPE_BAR_12();
    compute(L[2]); PIPE_BAR_0();
    compute(L[0]);

    #pragma unroll
    for (int m = 0; m < 4; m++)
        #pragma unroll
        for (int n = 0; n < 4; n++)
            #pragma unroll
            for (int r = 0; r < 4; r++) {
                const int row = m0 + w * 64 + m * 16 + lg * 4 + r;
                const int col = n0 + n * 16 + ll;
                out[row * 1024 + col] = acc[m][n][r] + X[row * 1024 + col];
            }
}

// ---------------------------------------------------------------- launch
extern "C" void kernel_launch(void* const* d_in, const int* in_sizes, int n_in,
                              void* d_out, int out_size, void* d_ws, size_t ws_size,
                              hipStream_t stream) {
    const float* X  = (const float*)d_in[0];
    const float* Wq = (const float*)d_in[1];
    const float* Wk = (const float*)d_in[2];
    const float* Wv = (const float*)d_in[3];
    const float* Wo = (const float*)d_in[4];
    float* out = (float*)d_out;

    char* ws = (char*)d_ws;
    float*          pos  = (float*)(ws);                                   // 512 KB
    unsigned short* Xbf  = (unsigned short*)(ws + (512u << 10));           // 8 MB (reused as attb)
    unsigned short* Wbf  = (unsigned short*)(ws + (512u << 10) + (8u  << 20));  // 8 MB (4 stacked)
    unsigned short* qb   = (unsigned short*)(ws + (512u << 10) + (16u << 20));
    unsigned short* kb   = (unsigned short*)(ws + (512u << 10) + (24u << 20));
    unsigned short* vt   = (unsigned short*)(ws + (512u << 10) + (32u << 20));
    unsigned short* attb = Xbf;   // Xbf dead after gemm_qkv; reuse for attn output

    cvt5<<<dim3(4608), dim3(256), 0, stream>>>(X, Wq, Wk, Wv, Wo, Xbf, Wbf, pos);
    gemm_qkv<<<dim3(16, 12), dim3(512), 0, stream>>>(Xbf, Wbf, pos, qb, kb, vt);
    attn_kernel<<<dim3(16, 32), dim3(512), 0, stream>>>(qb, kb, vt, attb);
    gemm_out<<<dim3(32, 16), dim3(128), 0, stream>>>(attb, Wbf, X, out);
}

// Round 16
// 91.768 us; speedup vs baseline: 1.1662x; 1.0398x over previous
//
#include <hip/hip_runtime.h>
#include <hip/hip_bf16.h>
#include <math.h>

#define S_LEN 2048
#define DMODEL 1024
#define NHEADS 16
#define DHEAD 64
#define NBATCH 2
#define MROWS (NBATCH * S_LEN)   // 4096

typedef float f32x4 __attribute__((ext_vector_type(4)));
typedef unsigned short u16x8 __attribute__((ext_vector_type(8)));
typedef __bf16 bf16x8 __attribute__((ext_vector_type(8)));

__device__ __forceinline__ f32x4 mfma16(u16x8 a, u16x8 b, f32x4 c) {
    return __builtin_amdgcn_mfma_f32_16x16x32_bf16(
        __builtin_bit_cast(bf16x8, a), __builtin_bit_cast(bf16x8, b), c, 0, 0, 0);
}

// f32 -> bf16 round-to-nearest-even
__device__ __forceinline__ unsigned short f2bf(float f) {
    unsigned int u = __builtin_bit_cast(unsigned int, f);
    u += 0x7FFFu + ((u >> 16) & 1u);
    return (unsigned short)(u >> 16);
}

// packed f32x2 -> bf16x2 (RTNE), single HW instruction; low16 = lo
__device__ __forceinline__ unsigned int cvtpk(float lo, float hi) {
    unsigned int r;
    asm("v_cvt_pk_bf16_f32 %0, %1, %2" : "=v"(r) : "v"(lo), "v"(hi));
    return r;
}

// async global->LDS, 16B per lane; lds dest = wave-uniform base + lane*16
__device__ __forceinline__ void gl16(const void* g, void* l) {
    __builtin_amdgcn_global_load_lds(
        (const __attribute__((address_space(1))) unsigned int*)g,
        (__attribute__((address_space(3))) unsigned int*)l, 16, 0, 0);
}

// counted-vmcnt publishing barrier (sched_barrier fences both sides)
#define VMB(N) do { \
    asm volatile("s_waitcnt vmcnt(" #N ")" ::: "memory"); \
    __builtin_amdgcn_sched_barrier(0); \
    __builtin_amdgcn_s_barrier(); \
    __builtin_amdgcn_sched_barrier(0); } while (0)
#define PIPE_BAR_12() do { \
    asm volatile("s_waitcnt vmcnt(12)" ::: "memory"); \
    __builtin_amdgcn_sched_barrier(0); \
    __builtin_amdgcn_s_barrier(); \
    __builtin_amdgcn_sched_barrier(0); } while (0)
#define PIPE_BAR_0() do { \
    asm volatile("s_waitcnt vmcnt(0)" ::: "memory"); \
    __builtin_amdgcn_sched_barrier(0); \
    __builtin_amdgcn_s_barrier(); \
    __builtin_amdgcn_sched_barrier(0); } while (0)

// ---------------------------------------------------------------- cvt + pos
// blocks 0..2047: X. 2048..4095: Wq,Wk,Wv,Wo. 4096..4607: pos table.
__global__ __launch_bounds__(256) void cvt5(
    const float* __restrict__ X, const float* __restrict__ Wq,
    const float* __restrict__ Wk, const float* __restrict__ Wv,
    const float* __restrict__ Wo,
    unsigned short* __restrict__ Xbf, unsigned short* __restrict__ Wbf,
    float* __restrict__ pos)
{
    int b = blockIdx.x;
    if (b >= 4096) {
        int i = (b - 4096) * 256 + threadIdx.x;
        int s = i >> 6, d = i & 63;
        float theta = powf(10000.0f, (2.0f * (float)d) / 64.0f);
        float x = (float)s / theta;
        float v = (d & 1) ? cosf(x) : sinf(x);
        pos[i] = (s == 0) ? 0.0f : v;
        return;
    }
    const float* s; unsigned short* d; int t;
    if (b < 2048) { s = X; d = Xbf; t = b * 256 + threadIdx.x; }
    else {
        int z = (b - 2048) >> 9, bb = (b - 2048) & 511;
        s = (z == 0) ? Wq : (z == 1) ? Wk : (z == 2) ? Wv : Wo;
        d = Wbf + (z << 20);
        t = bb * 256 + threadIdx.x;
    }
    float4 a = *((const float4*)s + t * 2);
    float4 c = *((const float4*)s + t * 2 + 1);
    u16x8 o;
    o[0] = f2bf(a.x); o[1] = f2bf(a.y); o[2] = f2bf(a.z); o[3] = f2bf(a.w);
    o[4] = f2bf(c.x); o[5] = f2bf(c.y); o[6] = f2bf(c.z); o[7] = f2bf(c.w);
    *((u16x8*)d + t) = o;
}

// ---------------------------------------------------------------- QKV GEMM (bf16 in)
// 256x192 tile, BK=64, 512 thr (8 waves, 2Mx4N; wave = 128x48), grid (16,16)
// = 256 blocks = exactly one full-machine generation. W treated as one
// [3072][1024] matrix (3 stacked); panels may straddle Q/K/V boundaries --
// epilogue derives z = col>>10 per nf (wave-uniform). LDS 2 x 56KB.
// Stage order per tile (7 gl16/thread): B0B1 | B2 | A0A2 | A1A3.
// Counted waits: mid-tile vmcnt(5) (oldest 2 = this tile's A13); boundary
// vmcnt(2) (oldest 5 = next tile's B + A02). Never 0 until tail.
__global__ __launch_bounds__(512) void gemm_qkv(
    const unsigned short* __restrict__ Xbf, const unsigned short* __restrict__ Wbf,
    const float* __restrict__ pos,
    unsigned short* __restrict__ qb, unsigned short* __restrict__ kb,
    unsigned short* __restrict__ vt)
{
    __shared__ unsigned short L[2][28672];   // 56KB per buffer: A @0 (16384 el), B @16384 (12288 el)
    const int t = threadIdx.x;               // 0..511
    const int lane = t & 63;
    const int w = t >> 6;                    // 0..7
    const int wm = w >> 2, wn = w & 3;
    const int m0 = blockIdx.x * 256;
    const int nb = blockIdx.y * 192;         // global col in [0,3072)
    const int ll = lane & 15, lg = lane >> 4;
    const int tr = t >> 3;                   // 0..63: row within each 64-row group
    const int ch = (t & 7) ^ (tr & 7);       // pre-swizzled source chunk

    f32x4 acc[8][3] = {};

    // running global stage pointers (advance 64 elems per K-tile)
    const unsigned short* gA[4];
    const unsigned short* gB[3];
    #pragma unroll
    for (int i = 0; i < 4; i++)
        gA[i] = Xbf + (m0 + i * 64 + tr) * 1024 + ch * 8;
    #pragma unroll
    for (int i = 0; i < 3; i++)
        gB[i] = Wbf + (nb + i * 64 + tr) * 1024 + ch * 8;

    const int sw0 = ((0 * 4 + lg) ^ (ll & 7)) * 16;
    const int sw1 = ((1 * 4 + lg) ^ (ll & 7)) * 16;
    const int aBase = (wm * 128 + ll) * 128;            // byte; + q*4096 + sw
    const int bBase = 32768 + (wn * 48 + ll) * 128;     // byte; + nf*2048 + sw
    const int wdst = w * 8 * 64;                        // elem; wave's stage rows

    auto stB01 = [&](unsigned short* Ln) {
        gl16(gB[0], Ln + 16384 + wdst);          gB[0] += 64;
        gl16(gB[1], Ln + 16384 + 4096 + wdst);   gB[1] += 64;
    };
    auto stB2 = [&](unsigned short* Ln) {
        gl16(gB[2], Ln + 16384 + 8192 + wdst);   gB[2] += 64;
    };
    auto stA02 = [&](unsigned short* Ln) {       // A rows 0-63, 128-191
        gl16(gA[0], Ln + wdst);                  gA[0] += 64;
        gl16(gA[2], Ln + 8192 + wdst);           gA[2] += 64;
    };
    auto stA13 = [&](unsigned short* Ln) {       // A rows 64-127, 192-255
        gl16(gA[1], Ln + 4096 + wdst);           gA[1] += 64;
        gl16(gA[3], Ln + 12288 + wdst);          gA[3] += 64;
    };

    u16x8 bf[3][2];
    auto loadB = [&](const char* bB) {
        #pragma unroll
        for (int nf = 0; nf < 3; nf++) {
            const char* p = bB + bBase + nf * 2048;
            bf[nf][0] = *(const u16x8*)(p + sw0);
            bf[nf][1] = *(const u16x8*)(p + sw1);
        }
    };
    auto quad = [&](int q, const char* bA) {
        const char* pa = bA + aBase + q * 4096;
        u16x8 a00 = *(const u16x8*)(pa + sw0);
        u16x8 a01 = *(const u16x8*)(pa + sw1);
        u16x8 a10 = *(const u16x8*)(pa + 2048 + sw0);
        u16x8 a11 = *(const u16x8*)(pa + 2048 + sw1);
        __builtin_amdgcn_s_setprio(1);
        #pragma unroll
        for (int nf = 0; nf < 3; nf++) {
            acc[q * 2 + 0][nf] = mfma16(a00, bf[nf][0], acc[q * 2 + 0][nf]);
            acc[q * 2 + 1][nf] = mfma16(a10, bf[nf][0], acc[q * 2 + 1][nf]);
        }
        #pragma unroll
        for (int nf = 0; nf < 3; nf++) {
            acc[q * 2 + 0][nf] = mfma16(a01, bf[nf][1], acc[q * 2 + 0][nf]);
            acc[q * 2 + 1][nf] = mfma16(a11, bf[nf][1], acc[q * 2 + 1][nf]);
        }
        __builtin_amdgcn_s_setprio(0);
    };

    // prologue: stage tile 0 in canonical order; boundary wait (A13 in flight)
    stB01(L[0]); stB2(L[0]); stA02(L[0]); stA13(L[0]);
    VMB(2);

    // tiles 0..14: compute buf tt&1, stage tile tt+1 into other buf
    #pragma unroll 1
    for (int tt = 0; tt < 15; tt++) {
        const char* bA = (const char*)L[tt & 1];
        unsigned short* Ln = L[(tt + 1) & 1];
        stB01(Ln);                    // P1
        loadB(bA);
        quad(0, bA);
        __builtin_amdgcn_s_barrier();
        stB2(Ln);                     // P2
        quad(1, bA);
        __builtin_amdgcn_s_barrier();
        stA02(Ln);                    // P3
        VMB(5);                       // publishes this tile's A13
        quad(2, bA);
        __builtin_amdgcn_s_barrier();
        stA13(Ln);                    // P4
        quad(3, bA);
        VMB(2);                       // boundary: next tile's B+A02 published
    }
    // tail tile 15 (no staging; only its A13 outstanding at mid-wait)
    {
        const char* bA = (const char*)L[1];
        loadB(bA);
        quad(0, bA);
        __builtin_amdgcn_s_barrier();
        quad(1, bA);
        VMB(0);                       // publish A13 of tile 15
        quad(2, bA);
        quad(3, bA);
    }

    // epilogue: z = col>>10 (wave-uniform per nf); route per matrix
    #pragma unroll
    for (int nf = 0; nf < 3; nf++) {
        const int c = nb + wn * 48 + nf * 16 + ll;   // global col 0..3071
        const int zz = c >> 10;                      // wave-uniform
        const int lc = c & 1023;
        const int h = lc >> 6, d = lc & 63;
        if (zz == 2) {
            #pragma unroll
            for (int mf = 0; mf < 8; mf++) {
                const int row0 = m0 + wm * 128 + mf * 16 + lg * 4;
                const int b = row0 >> 11, s0 = row0 & 2047;
                unsigned long long pk =
                    (unsigned long long)cvtpk(acc[mf][nf][0], acc[mf][nf][1]) |
                    ((unsigned long long)cvtpk(acc[mf][nf][2], acc[mf][nf][3]) << 32);
                *(unsigned long long*)&vt[(((b * NHEADS + h) * 64) + d) * S_LEN + s0] = pk;
            }
        } else {
            unsigned short* const dst = (zz == 0) ? qb : kb;
            const float pscale = (zz == 0) ? 0.1803368801111244f : 1.0f;
            #pragma unroll
            for (int mf = 0; mf < 8; mf++) {
                #pragma unroll
                for (int r = 0; r < 4; r++) {
                    const int row = m0 + wm * 128 + mf * 16 + lg * 4 + r;
                    const int b = row >> 11, s = row & 2047;
                    float v = acc[mf][nf][r] + pos[s * 64 + d];
                    v *= pscale;   // zz==0: fold 1/sqrt(d_k)*log2(e); zz==1: *1
                    dst[(((b * NHEADS + h) * S_LEN) + s) * 64 + d] = f2bf(v);
                }
            }
        }
    }
}

// ---------------------------------------------------------------- attention
// grid (16 qt, 32 bh), 8 waves x 512 thr, QBLK=128 (wave owns 16 q-rows).
// KVBLK=128: one barrier interval covers 128 KV rows (two 64-halves run
// back-to-back). K[2][128x64] + V^T[2][64x128] double-buffered (64KB) +
// per-wave P (16KB) = 80KB. Diagonal 128-tile peeled; waves 0-3 skip its
// fully-masked second half. Fixed-shift softmax exp2(sc).
__global__ __launch_bounds__(512, 4) void attn_kernel(
    const unsigned short* __restrict__ qb,
    const unsigned short* __restrict__ kb,
    const unsigned short* __restrict__ vt,
    unsigned short* __restrict__ attnb)
{
    __shared__ unsigned short Klds[2][128 * 64];   // 16KB each
    __shared__ unsigned short Vlds[2][64 * 128];   // 16KB each (row=d, 128 s-cols)
    __shared__ unsigned short Plds[8][16 * 64];    // per-wave 2KB; total 80KB

    const int bh = blockIdx.y;
    const int x = blockIdx.x;
    const int qt = (bh < 16) ? (15 - x) : x;      // pair long+short across halves

    const int lane = threadIdx.x & 63;
    const int w = threadIdx.x >> 6;               // 0..7
    const int lg = lane >> 4, ll = lane & 15;
    const int r8 = lane >> 3, ch = (lane & 7) ^ r8;
    const int r4 = lane >> 4, c16 = lane & 15;    // V-stage decomposition

    const unsigned short* Q = qb + bh * (S_LEN * 64);
    const unsigned short* K = kb + bh * (S_LEN * 64);
    const unsigned short* V = vt + bh * (64 * S_LEN);
    const int q0 = qt * 128 + w * 16;             // wave q-base

    u16x8 qf0 = *(const u16x8*)(Q + (q0 + ll) * 64 + lg * 8);
    u16x8 qf1 = *(const u16x8*)(Q + (q0 + ll) * 64 + 32 + lg * 8);

    f32x4 o_acc[4] = {};
    float l_part = 0.0f;

    // ---- precomputed LDS byte addresses ----
    const int sw0 = ((0 * 4 + lg) ^ (ll & 7)) * 16;
    const int sw1 = ((1 * 4 + lg) ^ (ll & 7)) * 16;
    // K read (row stride 128B): base + ll*128 + sw ; half1 = +8192 ; f-stride 2048
    const char* kb0p0 = (const char*)&Klds[0][0] + ll * 128 + sw0;
    const char* kb0p1 = (const char*)&Klds[0][0] + ll * 128 + sw1;
    const char* kb1p0 = (const char*)&Klds[1][0] + ll * 128 + sw0;
    const char* kb1p1 = (const char*)&Klds[1][0] + ll * 128 + sw1;
    // V read (row stride 256B): base + ll*256 + sw ; half1 = +128 ; f-stride 4096
    const char* vb0p0 = (const char*)&Vlds[0][0] + ll * 256 + sw0;
    const char* vb0p1 = (const char*)&Vlds[0][0] + ll * 256 + sw1;
    const char* vb1p0 = (const char*)&Vlds[1][0] + ll * 256 + sw0;
    const char* vb1p1 = (const char*)&Vlds[1][0] + ll * 256 + sw1;
    // P write: addr = ((ll*128+lg*8) ^ (E&16)) + ((f*32) ^ (E&96)),  E=(ll&7)<<4
    const int E = (ll & 7) << 4;
    char* pwb = (char*)&Plds[w][0] + (((ll * 128) + lg * 8) ^ (E & 16));
    const int pw_o0 = 0 ^ (E & 96), pw_o1 = 32 ^ (E & 96);
    const int pw_o2 = 64 ^ (E & 96), pw_o3 = 96 ^ (E & 96);
    const char* pr0 = (const char*)&Plds[w][0] + ll * 128 + sw0;
    const char* pr1 = (const char*)&Plds[w][0] + ll * 128 + sw1;
    // staging: K rows [w*16, +16) = 2 gl16; V rows [w*8, +8) = 2 gl16 (4 rows each)
    unsigned short* kd0 = &Klds[0][(w * 16) * 64];
    unsigned short* kd1 = &Klds[1][(w * 16) * 64];
    unsigned short* vd0 = &Vlds[0][(w * 8) * 128];
    unsigned short* vd1 = &Vlds[1][(w * 8) * 128];
    const unsigned short* gk  = K + (w * 16 + r8) * 64 + ch * 8;
    const unsigned short* gva = V + (w * 8 + r4) * S_LEN + ((c16 ^ r4) * 8);
    const unsigned short* gvb = V + (w * 8 + 4 + r4) * S_LEN + ((c16 ^ (4 + r4)) * 8);
    // diagonal thresholds: half0 thr = dthr, half1 thr = dthr - 64
    const int dthr = w * 16 + ll - lg * 4;

    auto stage2 = [&](unsigned short* kd, unsigned short* vd) {
        gl16(gk, kd);
        gl16(gk + 512, kd + 512);      // K rows +8
        gl16(gva, vd);
        gl16(gvb, vd + 512);           // V rows +4
        gk += 128 * 64;                // next 128-KV tile
        gva += 128;
        gvb += 128;
    };

    auto tile_body = [&](const char* kp0, const char* kp1,
                         const char* vp0, const char* vp1, bool masked, int thr) {
        f32x4 sc[4] = {};
        __builtin_amdgcn_s_setprio(1);
        #pragma unroll
        for (int f = 0; f < 4; f++) {
            const u16x8 kfa = *(const u16x8*)(kp0 + f * 2048);
            sc[f] = mfma16(kfa, qf0, sc[f]);
            const u16x8 kfb = *(const u16x8*)(kp1 + f * 2048);
            sc[f] = mfma16(kfb, qf1, sc[f]);
        }
        __builtin_amdgcn_s_setprio(0);
        if (masked) {
            #pragma unroll
            for (int f = 0; f < 4; f++)
                #pragma unroll
                for (int r = 0; r < 4; r++)
                    if (f * 16 + r > thr) sc[f][r] = -1.0e9f;
        }
        float ts = 0.0f;
        #pragma unroll
        for (int f = 0; f < 4; f++)
            #pragma unroll
            for (int r = 0; r < 4; r++) {
                const float p = __builtin_amdgcn_exp2f(sc[f][r]);
                sc[f][r] = p;
                ts += p;
            }
        l_part += ts;
        *(unsigned long long*)(pwb + pw_o0) =
            (unsigned long long)cvtpk(sc[0][0], sc[0][1]) | ((unsigned long long)cvtpk(sc[0][2], sc[0][3]) << 32);
        *(unsigned long long*)(pwb + pw_o1) =
            (unsigned long long)cvtpk(sc[1][0], sc[1][1]) | ((unsigned long long)cvtpk(sc[1][2], sc[1][3]) << 32);
        *(unsigned long long*)(pwb + pw_o2) =
            (unsigned long long)cvtpk(sc[2][0], sc[2][1]) | ((unsigned long long)cvtpk(sc[2][2], sc[2][3]) << 32);
        *(unsigned long long*)(pwb + pw_o3) =
            (unsigned long long)cvtpk(sc[3][0], sc[3][1]) | ((unsigned long long)cvtpk(sc[3][2], sc[3][3]) << 32);
        const u16x8 pf0 = *(const u16x8*)pr0;
        const u16x8 pf1 = *(const u16x8*)pr1;
        __builtin_amdgcn_s_setprio(1);
        #pragma unroll
        for (int f = 0; f < 4; f++) {
            o_acc[f] = mfma16(pf0, *(const u16x8*)(vp0 + f * 4096), o_acc[f]);
            o_acc[f] = mfma16(pf1, *(const u16x8*)(vp1 + f * 4096), o_acc[f]);
        }
        __builtin_amdgcn_s_setprio(0);
    };

    // body over one 128-KV buffer: two 64-halves
    auto body128_full = [&](const char* kp0, const char* kp1,
                            const char* vp0, const char* vp1) {
        tile_body(kp0, kp1, vp0, vp1, false, 0);
        tile_body(kp0 + 8192, kp1 + 8192, vp0 + 128, vp1 + 128, false, 0);
    };
    auto body128_diag = [&](const char* kp0, const char* kp1,
                            const char* vp0, const char* vp1) {
        tile_body(kp0, kp1, vp0, vp1, true, dthr);
        if (w >= 4)   // waves 0-3: second half fully masked
            tile_body(kp0 + 8192, kp1 + 8192, vp0 + 128, vp1 + 128, true, dthr - 64);
    };

    stage2(kd0, vd0);                      // tile 0 -> buf0
    __syncthreads();                       // buf0 ready

    int p = 0;
    while (p + 2 <= qt) {                  // two full 128-tiles
        stage2(kd1, vd1);                  // tile p+1 -> buf1
        body128_full(kb0p0, kb0p1, vb0p0, vb0p1);
        __syncthreads();                   // drains stage(p+1); buf1 ready
        stage2(kd0, vd0);                  // tile p+2 -> buf0
        body128_full(kb1p0, kb1p1, vb1p0, vb1p1);
        __syncthreads();                   // drains stage(p+2); buf0 ready
        p += 2;
    }
    if (p < qt) {                          // one full tile (p, buf0) + diag (buf1)
        stage2(kd1, vd1);                  // tile qt -> buf1
        body128_full(kb0p0, kb0p1, vb0p0, vb0p1);
        __syncthreads();
        body128_diag(kb1p0, kb1p1, vb1p0, vb1p1);
    } else {                               // diag in buf0
        body128_diag(kb0p0, kb0p1, vb0p0, vb0p1);
    }

    // one-time l reduction: lane (lg,ll) holds partial over its kv-subset of q=ll
    l_part += __shfl_xor(l_part, 16);
    l_part += __shfl_xor(l_part, 32);

    const int bb = bh >> 4, h = bh & 15;
    float lr0 = 1.0f / __shfl(l_part, lg * 4 + 0);
    float lr1 = 1.0f / __shfl(l_part, lg * 4 + 1);
    float lr2 = 1.0f / __shfl(l_part, lg * 4 + 2);
    float lr3 = 1.0f / __shfl(l_part, lg * 4 + 3);
    #pragma unroll
    for (int f = 0; f < 4; f++) {
        const int colbase = h * 64 + f * 16 + ll;
        attnb[(bb * S_LEN + q0 + lg * 4 + 0) * DMODEL + colbase] = f2bf(o_acc[f][0] * lr0);
        attnb[(bb * S_LEN + q0 + lg * 4 + 1) * DMODEL + colbase] = f2bf(o_acc[f][1] * lr1);
        attnb[(bb * S_LEN + q0 + lg * 4 + 2) * DMODEL + colbase] = f2bf(o_acc[f][2] * lr2);
        attnb[(bb * S_LEN + q0 + lg * 4 + 3) * DMODEL + colbase] = f2bf(o_acc[f][3] * lr3);
    }
}

// ---------------------------------------------------------------- out GEMM
// out = attn @ Wo^T + X. 3-buffer counted-vmcnt pipeline, 2-wave 128x64.
__global__ __launch_bounds__(128) void gemm_out(
    const unsigned short* __restrict__ Abf,
    const unsigned short* __restrict__ Wbf,
    const float* __restrict__ X,
    float* __restrict__ out)
{
    const unsigned short* __restrict__ W = Wbf + (3u << 20);
    __shared__ unsigned short L[3][192 * 64];   // 72KB
    const int t = threadIdx.x;
    const int lane = t & 63;
    const int w = t >> 6;
    const int m0 = blockIdx.x * 128;
    const int n0 = blockIdx.y * 64;
    const int ll = lane & 15, lg = lane >> 4;
    const int r8 = lane >> 3, ch = (lane & 7) ^ r8;

    f32x4 acc[4][4] = {};

    const unsigned short* gA[8];
    const unsigned short* gB[4];
    #pragma unroll
    for (int i = 0; i < 8; i++) gA[i] = Abf + (m0 + w * 64 + i * 8 + r8) * 1024 + ch * 8;
    #pragma unroll
    for (int i = 0; i < 4; i++) gB[i] = W + (n0 + w * 32 + i * 8 + r8) * 1024 + ch * 8;

    const int sw0 = ((0 * 4 + lg) ^ (ll & 7)) * 16;
    const int sw1 = ((1 * 4 + lg) ^ (ll & 7)) * 16;

    auto stage = [&](unsigned short* Lb) {
        unsigned short* const dA = Lb + (w * 64) * 64;
        unsigned short* const dB = Lb + 128 * 64 + (w * 32) * 64;
        #pragma unroll
        for (int i = 0; i < 8; i++) { gl16(gA[i], dA + i * 8 * 64); gA[i] += 64; }
        #pragma unroll
        for (int i = 0; i < 4; i++) { gl16(gB[i], dB + i * 8 * 64); gB[i] += 64; }
    };
    auto compute = [&](const unsigned short* Lb) {
        const char* const pA0 = (const char*)Lb + (w * 64 + ll) * 128 + sw0;
        const char* const pA1 = (const char*)Lb + (w * 64 + ll) * 128 + sw1;
        const char* const pB0 = (const char*)Lb + 16384 + ll * 128 + sw0;
        const char* const pB1 = (const char*)Lb + 16384 + ll * 128 + sw1;
        u16x8 af[4], bfv[4];
        #pragma unroll
        for (int m = 0; m < 4; m++) af[m] = *(const u16x8*)(pA0 + m * 2048);
        #pragma unroll
        for (int n = 0; n < 4; n++) bfv[n] = *(const u16x8*)(pB0 + n * 2048);
        __builtin_amdgcn_s_setprio(1);
        #pragma unroll
        for (int m = 0; m < 4; m++)
            #pragma unroll
            for (int n = 0; n < 4; n++)
                acc[m][n] = mfma16(af[m], bfv[n], acc[m][n]);
        __builtin_amdgcn_s_setprio(0);
        #pragma unroll
        for (int m = 0; m < 4; m++) af[m] = *(const u16x8*)(pA1 + m * 2048);
        #pragma unroll
        for (int n = 0; n < 4; n++) bfv[n] = *(const u16x8*)(pB1 + n * 2048);
        __builtin_amdgcn_s_setprio(1);
        #pragma unroll
        for (int m = 0; m < 4; m++)
            #pragma unroll
            for (int n = 0; n < 4; n++)
                acc[m][n] = mfma16(af[m], bfv[n], acc[m][n]);
        __builtin_amdgcn_s_setprio(0);
    };

    stage(L[0]);
    stage(L[1]);
    PIPE_BAR_12();
    for (int tt = 0; tt < 4; tt++) {
        stage(L[2]); compute(L[0]); PIPE_BAR_12();
        stage(L[0]); compute(L[1]); PIPE_BAR_12();
        stage(L[1]); compute(L[2]); PIPE_BAR_12();
    }
    stage(L[2]); compute(L[0]); PIPE_BAR_12();
    stage(L[0]); compute(L[1]); PIPE_BAR_12();
    compute(L[2]); PIPE_BAR_0();
    compute(L[0]);

    #pragma unroll
    for (int m = 0; m < 4; m++)
        #pragma unroll
        for (int n = 0; n < 4; n++)
            #pragma unroll
            for (int r = 0; r < 4; r++) {
                const int row = m0 + w * 64 + m * 16 + lg * 4 + r;
                const int col = n0 + n * 16 + ll;
                out[row * 1024 + col] = acc[m][n][r] + X[row * 1024 + col];
            }
}

// ---------------------------------------------------------------- launch
extern "C" void kernel_launch(void* const* d_in, const int* in_sizes, int n_in,
                              void* d_out, int out_size, void* d_ws, size_t ws_size,
                              hipStream_t stream) {
    const float* X  = (const float*)d_in[0];
    const float* Wq = (const float*)d_in[1];
    const float* Wk = (const float*)d_in[2];
    const float* Wv = (const float*)d_in[3];
    const float* Wo = (const float*)d_in[4];
    float* out = (float*)d_out;

    char* ws = (char*)d_ws;
    float*          pos  = (float*)(ws);                                   // 512 KB
    unsigned short* Xbf  = (unsigned short*)(ws + (512u << 10));           // 8 MB (reused as attb)
    unsigned short* Wbf  = (unsigned short*)(ws + (512u << 10) + (8u  << 20));  // 8 MB (4 stacked)
    unsigned short* qb   = (unsigned short*)(ws + (512u << 10) + (16u << 20));
    unsigned short* kb   = (unsigned short*)(ws + (512u << 10) + (24u << 20));
    unsigned short* vt   = (unsigned short*)(ws + (512u << 10) + (32u << 20));
    unsigned short* attb = Xbf;   // Xbf dead after gemm_qkv; reuse for attn output

    cvt5<<<dim3(4608), dim3(256), 0, stream>>>(X, Wq, Wk, Wv, Wo, Xbf, Wbf, pos);
    gemm_qkv<<<dim3(16, 16), dim3(512), 0, stream>>>(Xbf, Wbf, pos, qb, kb, vt);
    attn_kernel<<<dim3(16, 32), dim3(512), 0, stream>>>(qb, kb, vt, attb);
    gemm_out<<<dim3(32, 16), dim3(128), 0, stream>>>(attb, Wbf, X, out);
}

// Round 17
// 90.588 us; speedup vs baseline: 1.1814x; 1.0130x over previous
//
#include <hip/hip_runtime.h>
#include <hip/hip_bf16.h>
#include <math.h>

#define S_LEN 2048
#define DMODEL 1024
#define NHEADS 16
#define DHEAD 64
#define NBATCH 2
#define MROWS (NBATCH * S_LEN)   // 4096

typedef float f32x4 __attribute__((ext_vector_type(4)));
typedef unsigned short u16x8 __attribute__((ext_vector_type(8)));
typedef __bf16 bf16x8 __attribute__((ext_vector_type(8)));

__device__ __forceinline__ f32x4 mfma16(u16x8 a, u16x8 b, f32x4 c) {
    return __builtin_amdgcn_mfma_f32_16x16x32_bf16(
        __builtin_bit_cast(bf16x8, a), __builtin_bit_cast(bf16x8, b), c, 0, 0, 0);
}

// f32 -> bf16 round-to-nearest-even
__device__ __forceinline__ unsigned short f2bf(float f) {
    unsigned int u = __builtin_bit_cast(unsigned int, f);
    u += 0x7FFFu + ((u >> 16) & 1u);
    return (unsigned short)(u >> 16);
}

// packed f32x2 -> bf16x2 (RTNE), single HW instruction; low16 = lo
__device__ __forceinline__ unsigned int cvtpk(float lo, float hi) {
    unsigned int r;
    asm("v_cvt_pk_bf16_f32 %0, %1, %2" : "=v"(r) : "v"(lo), "v"(hi));
    return r;
}

// async global->LDS, 16B per lane; lds dest = wave-uniform base + lane*16
__device__ __forceinline__ void gl16(const void* g, void* l) {
    __builtin_amdgcn_global_load_lds(
        (const __attribute__((address_space(1))) unsigned int*)g,
        (__attribute__((address_space(3))) unsigned int*)l, 16, 0, 0);
}

// counted-vmcnt publishing barrier (sched_barrier fences both sides)
#define VMB(N) do { \
    asm volatile("s_waitcnt vmcnt(" #N ")" ::: "memory"); \
    __builtin_amdgcn_sched_barrier(0); \
    __builtin_amdgcn_s_barrier(); \
    __builtin_amdgcn_sched_barrier(0); } while (0)
#define PIPE_BAR_12() do { \
    asm volatile("s_waitcnt vmcnt(12)" ::: "memory"); \
    __builtin_amdgcn_sched_barrier(0); \
    __builtin_amdgcn_s_barrier(); \
    __builtin_amdgcn_sched_barrier(0); } while (0)
#define PIPE_BAR_0() do { \
    asm volatile("s_waitcnt vmcnt(0)" ::: "memory"); \
    __builtin_amdgcn_sched_barrier(0); \
    __builtin_amdgcn_s_barrier(); \
    __builtin_amdgcn_sched_barrier(0); } while (0)

// ---------------------------------------------------------------- cvt + pos
// blocks 0..2047: X. 2048..4095: Wq,Wk,Wv,Wo. 4096..4607: pos table.
__global__ __launch_bounds__(256) void cvt5(
    const float* __restrict__ X, const float* __restrict__ Wq,
    const float* __restrict__ Wk, const float* __restrict__ Wv,
    const float* __restrict__ Wo,
    unsigned short* __restrict__ Xbf, unsigned short* __restrict__ Wbf,
    float* __restrict__ pos)
{
    int b = blockIdx.x;
    if (b >= 4096) {
        int i = (b - 4096) * 256 + threadIdx.x;
        int s = i >> 6, d = i & 63;
        float theta = powf(10000.0f, (2.0f * (float)d) / 64.0f);
        float x = (float)s / theta;
        float v = (d & 1) ? cosf(x) : sinf(x);
        pos[i] = (s == 0) ? 0.0f : v;
        return;
    }
    const float* s; unsigned short* d; int t;
    if (b < 2048) { s = X; d = Xbf; t = b * 256 + threadIdx.x; }
    else {
        int z = (b - 2048) >> 9, bb = (b - 2048) & 511;
        s = (z == 0) ? Wq : (z == 1) ? Wk : (z == 2) ? Wv : Wo;
        d = Wbf + (z << 20);
        t = bb * 256 + threadIdx.x;
    }
    float4 a = *((const float4*)s + t * 2);
    float4 c = *((const float4*)s + t * 2 + 1);
    u16x8 o;
    o[0] = f2bf(a.x); o[1] = f2bf(a.y); o[2] = f2bf(a.z); o[3] = f2bf(a.w);
    o[4] = f2bf(c.x); o[5] = f2bf(c.y); o[6] = f2bf(c.z); o[7] = f2bf(c.w);
    *((u16x8*)d + t) = o;
}

// ---------------------------------------------------------------- QKV GEMM (bf16 in)
// 256x192 tile, BK=64, 512 thr (8 waves, 2Mx4N; wave = 128x48), grid (16,16)
// = 256 blocks = exactly one full-machine generation. W treated as one
// [3072][1024] matrix (3 stacked); panels may straddle Q/K/V boundaries --
// epilogue derives z = col>>10 per nf (wave-uniform). LDS 2 x 56KB.
// Stage order per tile (7 gl16/thread): B0B1 | B2 | A0A2 | A1A3.
// Counted waits: mid-tile vmcnt(5); boundary vmcnt(2). Never 0 until tail.
__global__ __launch_bounds__(512) void gemm_qkv(
    const unsigned short* __restrict__ Xbf, const unsigned short* __restrict__ Wbf,
    const float* __restrict__ pos,
    unsigned short* __restrict__ qb, unsigned short* __restrict__ kb,
    unsigned short* __restrict__ vt)
{
    __shared__ unsigned short L[2][28672];   // 56KB per buffer: A @0 (16384 el), B @16384 (12288 el)
    const int t = threadIdx.x;               // 0..511
    const int lane = t & 63;
    const int w = t >> 6;                    // 0..7
    const int wm = w >> 2, wn = w & 3;
    const int m0 = blockIdx.x * 256;
    const int nb = blockIdx.y * 192;         // global col in [0,3072)
    const int ll = lane & 15, lg = lane >> 4;
    const int tr = t >> 3;                   // 0..63: row within each 64-row group
    const int ch = (t & 7) ^ (tr & 7);       // pre-swizzled source chunk

    f32x4 acc[8][3] = {};

    const unsigned short* gA[4];
    const unsigned short* gB[3];
    #pragma unroll
    for (int i = 0; i < 4; i++)
        gA[i] = Xbf + (m0 + i * 64 + tr) * 1024 + ch * 8;
    #pragma unroll
    for (int i = 0; i < 3; i++)
        gB[i] = Wbf + (nb + i * 64 + tr) * 1024 + ch * 8;

    const int sw0 = ((0 * 4 + lg) ^ (ll & 7)) * 16;
    const int sw1 = ((1 * 4 + lg) ^ (ll & 7)) * 16;
    const int aBase = (wm * 128 + ll) * 128;            // byte; + q*4096 + sw
    const int bBase = 32768 + (wn * 48 + ll) * 128;     // byte; + nf*2048 + sw
    const int wdst = w * 8 * 64;                        // elem; wave's stage rows

    auto stB01 = [&](unsigned short* Ln) {
        gl16(gB[0], Ln + 16384 + wdst);          gB[0] += 64;
        gl16(gB[1], Ln + 16384 + 4096 + wdst);   gB[1] += 64;
    };
    auto stB2 = [&](unsigned short* Ln) {
        gl16(gB[2], Ln + 16384 + 8192 + wdst);   gB[2] += 64;
    };
    auto stA02 = [&](unsigned short* Ln) {       // A rows 0-63, 128-191
        gl16(gA[0], Ln + wdst);                  gA[0] += 64;
        gl16(gA[2], Ln + 8192 + wdst);           gA[2] += 64;
    };
    auto stA13 = [&](unsigned short* Ln) {       // A rows 64-127, 192-255
        gl16(gA[1], Ln + 4096 + wdst);           gA[1] += 64;
        gl16(gA[3], Ln + 12288 + wdst);          gA[3] += 64;
    };

    u16x8 bf[3][2];
    auto loadB = [&](const char* bB) {
        #pragma unroll
        for (int nf = 0; nf < 3; nf++) {
            const char* p = bB + bBase + nf * 2048;
            bf[nf][0] = *(const u16x8*)(p + sw0);
            bf[nf][1] = *(const u16x8*)(p + sw1);
        }
    };
    auto quad = [&](int q, const char* bA) {
        const char* pa = bA + aBase + q * 4096;
        u16x8 a00 = *(const u16x8*)(pa + sw0);
        u16x8 a01 = *(const u16x8*)(pa + sw1);
        u16x8 a10 = *(const u16x8*)(pa + 2048 + sw0);
        u16x8 a11 = *(const u16x8*)(pa + 2048 + sw1);
        __builtin_amdgcn_s_setprio(1);
        #pragma unroll
        for (int nf = 0; nf < 3; nf++) {
            acc[q * 2 + 0][nf] = mfma16(a00, bf[nf][0], acc[q * 2 + 0][nf]);
            acc[q * 2 + 1][nf] = mfma16(a10, bf[nf][0], acc[q * 2 + 1][nf]);
        }
        #pragma unroll
        for (int nf = 0; nf < 3; nf++) {
            acc[q * 2 + 0][nf] = mfma16(a01, bf[nf][1], acc[q * 2 + 0][nf]);
            acc[q * 2 + 1][nf] = mfma16(a11, bf[nf][1], acc[q * 2 + 1][nf]);
        }
        __builtin_amdgcn_s_setprio(0);
    };

    // prologue: stage tile 0 in canonical order; boundary wait (A13 in flight)
    stB01(L[0]); stB2(L[0]); stA02(L[0]); stA13(L[0]);
    VMB(2);

    // tiles 0..14: compute buf tt&1, stage tile tt+1 into other buf
    #pragma unroll 1
    for (int tt = 0; tt < 15; tt++) {
        const char* bA = (const char*)L[tt & 1];
        unsigned short* Ln = L[(tt + 1) & 1];
        stB01(Ln);                    // P1
        loadB(bA);
        quad(0, bA);
        __builtin_amdgcn_s_barrier();
        stB2(Ln);                     // P2
        quad(1, bA);
        __builtin_amdgcn_s_barrier();
        stA02(Ln);                    // P3
        VMB(5);                       // publishes this tile's A13
        quad(2, bA);
        __builtin_amdgcn_s_barrier();
        stA13(Ln);                    // P4
        quad(3, bA);
        VMB(2);                       // boundary: next tile's B+A02 published
    }
    // tail tile 15 (no staging; only its A13 outstanding at mid-wait)
    {
        const char* bA = (const char*)L[1];
        loadB(bA);
        quad(0, bA);
        __builtin_amdgcn_s_barrier();
        quad(1, bA);
        VMB(0);                       // publish A13 of tile 15
        quad(2, bA);
        quad(3, bA);
    }

    // epilogue: z = col>>10 (wave-uniform per nf); route per matrix
    #pragma unroll
    for (int nf = 0; nf < 3; nf++) {
        const int c = nb + wn * 48 + nf * 16 + ll;   // global col 0..3071
        const int zz = c >> 10;                      // wave-uniform
        const int lc = c & 1023;
        const int h = lc >> 6, d = lc & 63;
        if (zz == 2) {
            #pragma unroll
            for (int mf = 0; mf < 8; mf++) {
                const int row0 = m0 + wm * 128 + mf * 16 + lg * 4;
                const int b = row0 >> 11, s0 = row0 & 2047;
                unsigned long long pk =
                    (unsigned long long)cvtpk(acc[mf][nf][0], acc[mf][nf][1]) |
                    ((unsigned long long)cvtpk(acc[mf][nf][2], acc[mf][nf][3]) << 32);
                *(unsigned long long*)&vt[(((b * NHEADS + h) * 64) + d) * S_LEN + s0] = pk;
            }
        } else {
            unsigned short* const dst = (zz == 0) ? qb : kb;
            const float pscale = (zz == 0) ? 0.1803368801111244f : 1.0f;
            #pragma unroll
            for (int mf = 0; mf < 8; mf++) {
                #pragma unroll
                for (int r = 0; r < 4; r++) {
                    const int row = m0 + wm * 128 + mf * 16 + lg * 4 + r;
                    const int b = row >> 11, s = row & 2047;
                    float v = acc[mf][nf][r] + pos[s * 64 + d];
                    v *= pscale;   // zz==0: fold 1/sqrt(d_k)*log2(e); zz==1: *1
                    dst[(((b * NHEADS + h) * S_LEN) + s) * 64 + d] = f2bf(v);
                }
            }
        }
    }
}

// ---------------------------------------------------------------- attention
// grid (16 qt, 32 bh), 8 waves x 512 thr, QBLK=128 (wave owns 16 q-rows).
// KVBLK=128. Softmax denominator computed on the MATRIX pipe: l = P x ones
// via one extra MFMA per kk (shares the PV A-fragment). Lane (lg,ll)'s
// l_acc[r] is exactly the denominator for output row q0+lg*4+r -- no adds,
// no shuffles. Masked elems contribute exp2(-1e9)=0 to both l and PV.
// Fixed-shift softmax exp2(sc). Diagonal 128-tile peeled.
__global__ __launch_bounds__(512, 4) void attn_kernel(
    const unsigned short* __restrict__ qb,
    const unsigned short* __restrict__ kb,
    const unsigned short* __restrict__ vt,
    unsigned short* __restrict__ attnb)
{
    __shared__ unsigned short Klds[2][128 * 64];   // 16KB each
    __shared__ unsigned short Vlds[2][64 * 128];   // 16KB each (row=d, 128 s-cols)
    __shared__ unsigned short Plds[8][16 * 64];    // per-wave 2KB; total 80KB

    const int bh = blockIdx.y;
    const int x = blockIdx.x;
    const int qt = (bh < 16) ? (15 - x) : x;      // pair long+short across halves

    const int lane = threadIdx.x & 63;
    const int w = threadIdx.x >> 6;               // 0..7
    const int lg = lane >> 4, ll = lane & 15;
    const int r8 = lane >> 3, ch = (lane & 7) ^ r8;
    const int r4 = lane >> 4, c16 = lane & 15;    // V-stage decomposition

    const unsigned short* Q = qb + bh * (S_LEN * 64);
    const unsigned short* K = kb + bh * (S_LEN * 64);
    const unsigned short* V = vt + bh * (64 * S_LEN);
    const int q0 = qt * 128 + w * 16;             // wave q-base

    u16x8 qf0 = *(const u16x8*)(Q + (q0 + ll) * 64 + lg * 8);
    u16x8 qf1 = *(const u16x8*)(Q + (q0 + ll) * 64 + 32 + lg * 8);

    // all-ones bf16 fragment for the l-MFMA (1.0bf16 = 0x3F80)
    u16x8 ones;
    #pragma unroll
    for (int i = 0; i < 8; i++) ones[i] = 0x3F80;

    f32x4 o_acc[4] = {};
    f32x4 l_acc = {};

    // ---- precomputed LDS byte addresses ----
    const int sw0 = ((0 * 4 + lg) ^ (ll & 7)) * 16;
    const int sw1 = ((1 * 4 + lg) ^ (ll & 7)) * 16;
    // K read (row stride 128B): base + ll*128 + sw ; half1 = +8192 ; f-stride 2048
    const char* kb0p0 = (const char*)&Klds[0][0] + ll * 128 + sw0;
    const char* kb0p1 = (const char*)&Klds[0][0] + ll * 128 + sw1;
    const char* kb1p0 = (const char*)&Klds[1][0] + ll * 128 + sw0;
    const char* kb1p1 = (const char*)&Klds[1][0] + ll * 128 + sw1;
    // V read (row stride 256B): base + ll*256 + sw ; half1 = +128 ; f-stride 4096
    const char* vb0p0 = (const char*)&Vlds[0][0] + ll * 256 + sw0;
    const char* vb0p1 = (const char*)&Vlds[0][0] + ll * 256 + sw1;
    const char* vb1p0 = (const char*)&Vlds[1][0] + ll * 256 + sw0;
    const char* vb1p1 = (const char*)&Vlds[1][0] + ll * 256 + sw1;
    // P write: addr = ((ll*128+lg*8) ^ (E&16)) + ((f*32) ^ (E&96)),  E=(ll&7)<<4
    const int E = (ll & 7) << 4;
    char* pwb = (char*)&Plds[w][0] + (((ll * 128) + lg * 8) ^ (E & 16));
    const int pw_o0 = 0 ^ (E & 96), pw_o1 = 32 ^ (E & 96);
    const int pw_o2 = 64 ^ (E & 96), pw_o3 = 96 ^ (E & 96);
    const char* pr0 = (const char*)&Plds[w][0] + ll * 128 + sw0;
    const char* pr1 = (const char*)&Plds[w][0] + ll * 128 + sw1;
    // staging: K rows [w*16, +16) = 2 gl16; V rows [w*8, +8) = 2 gl16 (4 rows each)
    unsigned short* kd0 = &Klds[0][(w * 16) * 64];
    unsigned short* kd1 = &Klds[1][(w * 16) * 64];
    unsigned short* vd0 = &Vlds[0][(w * 8) * 128];
    unsigned short* vd1 = &Vlds[1][(w * 8) * 128];
    const unsigned short* gk  = K + (w * 16 + r8) * 64 + ch * 8;
    const unsigned short* gva = V + (w * 8 + r4) * S_LEN + ((c16 ^ r4) * 8);
    const unsigned short* gvb = V + (w * 8 + 4 + r4) * S_LEN + ((c16 ^ (4 + r4)) * 8);
    // diagonal thresholds: half0 thr = dthr, half1 thr = dthr - 64
    const int dthr = w * 16 + ll - lg * 4;

    auto stage2 = [&](unsigned short* kd, unsigned short* vd) {
        gl16(gk, kd);
        gl16(gk + 512, kd + 512);      // K rows +8
        gl16(gva, vd);
        gl16(gvb, vd + 512);           // V rows +4
        gk += 128 * 64;                // next 128-KV tile
        gva += 128;
        gvb += 128;
    };

    auto tile_body = [&](const char* kp0, const char* kp1,
                         const char* vp0, const char* vp1, bool masked, int thr) {
        f32x4 sc[4] = {};
        __builtin_amdgcn_s_setprio(1);
        #pragma unroll
        for (int f = 0; f < 4; f++) {
            const u16x8 kfa = *(const u16x8*)(kp0 + f * 2048);
            sc[f] = mfma16(kfa, qf0, sc[f]);
            const u16x8 kfb = *(const u16x8*)(kp1 + f * 2048);
            sc[f] = mfma16(kfb, qf1, sc[f]);
        }
        __builtin_amdgcn_s_setprio(0);
        if (masked) {
            #pragma unroll
            for (int f = 0; f < 4; f++)
                #pragma unroll
                for (int r = 0; r < 4; r++)
                    if (f * 16 + r > thr) sc[f][r] = -1.0e9f;
        }
        #pragma unroll
        for (int f = 0; f < 4; f++)
            #pragma unroll
            for (int r = 0; r < 4; r++)
                sc[f][r] = __builtin_amdgcn_exp2f(sc[f][r]);
        *(unsigned long long*)(pwb + pw_o0) =
            (unsigned long long)cvtpk(sc[0][0], sc[0][1]) | ((unsigned long long)cvtpk(sc[0][2], sc[0][3]) << 32);
        *(unsigned long long*)(pwb + pw_o1) =
            (unsigned long long)cvtpk(sc[1][0], sc[1][1]) | ((unsigned long long)cvtpk(sc[1][2], sc[1][3]) << 32);
        *(unsigned long long*)(pwb + pw_o2) =
            (unsigned long long)cvtpk(sc[2][0], sc[2][1]) | ((unsigned long long)cvtpk(sc[2][2], sc[2][3]) << 32);
        *(unsigned long long*)(pwb + pw_o3) =
            (unsigned long long)cvtpk(sc[3][0], sc[3][1]) | ((unsigned long long)cvtpk(sc[3][2], sc[3][3]) << 32);
        const u16x8 pf0 = *(const u16x8*)pr0;
        const u16x8 pf1 = *(const u16x8*)pr1;
        __builtin_amdgcn_s_setprio(1);
        #pragma unroll
        for (int f = 0; f < 4; f++) {
            o_acc[f] = mfma16(pf0, *(const u16x8*)(vp0 + f * 4096), o_acc[f]);
            o_acc[f] = mfma16(pf1, *(const u16x8*)(vp1 + f * 4096), o_acc[f]);
        }
        l_acc = mfma16(pf0, ones, l_acc);   // l += P x 1 (matrix pipe)
        l_acc = mfma16(pf1, ones, l_acc);
        __builtin_amdgcn_s_setprio(0);
    };

    // body over one 128-KV buffer: two 64-halves
    auto body128_full = [&](const char* kp0, const char* kp1,
                            const char* vp0, const char* vp1) {
        tile_body(kp0, kp1, vp0, vp1, false, 0);
        tile_body(kp0 + 8192, kp1 + 8192, vp0 + 128, vp1 + 128, false, 0);
    };
    auto body128_diag = [&](const char* kp0, const char* kp1,
                            const char* vp0, const char* vp1) {
        tile_body(kp0, kp1, vp0, vp1, true, dthr);
        if (w >= 4)   // waves 0-3: second half fully masked
            tile_body(kp0 + 8192, kp1 + 8192, vp0 + 128, vp1 + 128, true, dthr - 64);
    };

    stage2(kd0, vd0);                      // tile 0 -> buf0
    __syncthreads();                       // buf0 ready

    int p = 0;
    while (p + 2 <= qt) {                  // two full 128-tiles
        stage2(kd1, vd1);                  // tile p+1 -> buf1
        body128_full(kb0p0, kb0p1, vb0p0, vb0p1);
        __syncthreads();                   // drains stage(p+1); buf1 ready
        stage2(kd0, vd0);                  // tile p+2 -> buf0
        body128_full(kb1p0, kb1p1, vb1p0, vb1p1);
        __syncthreads();                   // drains stage(p+2); buf0 ready
        p += 2;
    }
    if (p < qt) {                          // one full tile (p, buf0) + diag (buf1)
        stage2(kd1, vd1);                  // tile qt -> buf1
        body128_full(kb0p0, kb0p1, vb0p0, vb0p1);
        __syncthreads();
        body128_diag(kb1p0, kb1p1, vb1p0, vb1p1);
    } else {                               // diag in buf0
        body128_diag(kb0p0, kb0p1, vb0p0, vb0p1);
    }

    const int bb = bh >> 4, h = bh & 15;
    const float lr0 = 1.0f / l_acc[0];
    const float lr1 = 1.0f / l_acc[1];
    const float lr2 = 1.0f / l_acc[2];
    const float lr3 = 1.0f / l_acc[3];
    #pragma unroll
    for (int f = 0; f < 4; f++) {
        const int colbase = h * 64 + f * 16 + ll;
        attnb[(bb * S_LEN + q0 + lg * 4 + 0) * DMODEL + colbase] = f2bf(o_acc[f][0] * lr0);
        attnb[(bb * S_LEN + q0 + lg * 4 + 1) * DMODEL + colbase] = f2bf(o_acc[f][1] * lr1);
        attnb[(bb * S_LEN + q0 + lg * 4 + 2) * DMODEL + colbase] = f2bf(o_acc[f][2] * lr2);
        attnb[(bb * S_LEN + q0 + lg * 4 + 3) * DMODEL + colbase] = f2bf(o_acc[f][3] * lr3);
    }
}

// ---------------------------------------------------------------- out GEMM
// out = attn @ Wo^T + X. 3-buffer counted-vmcnt pipeline, 2-wave 128x64.
__global__ __launch_bounds__(128) void gemm_out(
    const unsigned short* __restrict__ Abf,
    const unsigned short* __restrict__ Wbf,
    const float* __restrict__ X,
    float* __restrict__ out)
{
    const unsigned short* __restrict__ W = Wbf + (3u << 20);
    __shared__ unsigned short L[3][192 * 64];   // 72KB
    const int t = threadIdx.x;
    const int lane = t & 63;
    const int w = t >> 6;
    const int m0 = blockIdx.x * 128;
    const int n0 = blockIdx.y * 64;
    const int ll = lane & 15, lg = lane >> 4;
    const int r8 = lane >> 3, ch = (lane & 7) ^ r8;

    f32x4 acc[4][4] = {};

    const unsigned short* gA[8];
    const unsigned short* gB[4];
    #pragma unroll
    for (int i = 0; i < 8; i++) gA[i] = Abf + (m0 + w * 64 + i * 8 + r8) * 1024 + ch * 8;
    #pragma unroll
    for (int i = 0; i < 4; i++) gB[i] = W + (n0 + w * 32 + i * 8 + r8) * 1024 + ch * 8;

    const int sw0 = ((0 * 4 + lg) ^ (ll & 7)) * 16;
    const int sw1 = ((1 * 4 + lg) ^ (ll & 7)) * 16;

    auto stage = [&](unsigned short* Lb) {
        unsigned short* const dA = Lb + (w * 64) * 64;
        unsigned short* const dB = Lb + 128 * 64 + (w * 32) * 64;
        #pragma unroll
        for (int i = 0; i < 8; i++) { gl16(gA[i], dA + i * 8 * 64); gA[i] += 64; }
        #pragma unroll
        for (int i = 0; i < 4; i++) { gl16(gB[i], dB + i * 8 * 64); gB[i] += 64; }
    };
    auto compute = [&](const unsigned short* Lb) {
        const char* const pA0 = (const char*)Lb + (w * 64 + ll) * 128 + sw0;
        const char* const pA1 = (const char*)Lb + (w * 64 + ll) * 128 + sw1;
        const char* const pB0 = (const char*)Lb + 16384 + ll * 128 + sw0;
        const char* const pB1 = (const char*)Lb + 16384 + ll * 128 + sw1;
        u16x8 af[4], bfv[4];
        #pragma unroll
        for (int m = 0; m < 4; m++) af[m] = *(const u16x8*)(pA0 + m * 2048);
        #pragma unroll
        for (int n = 0; n < 4; n++) bfv[n] = *(const u16x8*)(pB0 + n * 2048);
        __builtin_amdgcn_s_setprio(1);
        #pragma unroll
        for (int m = 0; m < 4; m++)
            #pragma unroll
            for (int n = 0; n < 4; n++)
                acc[m][n] = mfma16(af[m], bfv[n], acc[m][n]);
        __builtin_amdgcn_s_setprio(0);
        #pragma unroll
        for (int m = 0; m < 4; m++) af[m] = *(const u16x8*)(pA1 + m * 2048);
        #pragma unroll
        for (int n = 0; n < 4; n++) bfv[n] = *(const u16x8*)(pB1 + n * 2048);
        __builtin_amdgcn_s_setprio(1);
        #pragma unroll
        for (int m = 0; m < 4; m++)
            #pragma unroll
            for (int n = 0; n < 4; n++)
                acc[m][n] = mfma16(af[m], bfv[n], acc[m][n]);
        __builtin_amdgcn_s_setprio(0);
    };

    stage(L[0]);
    stage(L[1]);
    PIPE_BAR_12();
    for (int tt = 0; tt < 4; tt++) {
        stage(L[2]); compute(L[0]); PIPE_BAR_12();
        stage(L[0]); compute(L[1]); PIPE_BAR_12();
        stage(L[1]); compute(L[2]); PIPE_BAR_12();
    }
    stage(L[2]); compute(L[0]); PIPE_BAR_12();
    stage(L[0]); compute(L[1]); PIPE_BAR_12();
    compute(L[2]); PIPE_BAR_0();
    compute(L[0]);

    #pragma unroll
    for (int m = 0; m < 4; m++)
        #pragma unroll
        for (int n = 0; n < 4; n++)
            #pragma unroll
            for (int r = 0; r < 4; r++) {
                const int row = m0 + w * 64 + m * 16 + lg * 4 + r;
                const int col = n0 + n * 16 + ll;
                out[row * 1024 + col] = acc[m][n][r] + X[row * 1024 + col];
            }
}

// ---------------------------------------------------------------- launch
extern "C" void kernel_launch(void* const* d_in, const int* in_sizes, int n_in,
                              void* d_out, int out_size, void* d_ws, size_t ws_size,
                              hipStream_t stream) {
    const float* X  = (const float*)d_in[0];
    const float* Wq = (const float*)d_in[1];
    const float* Wk = (const float*)d_in[2];
    const float* Wv = (const float*)d_in[3];
    const float* Wo = (const float*)d_in[4];
    float* out = (float*)d_out;

    char* ws = (char*)d_ws;
    float*          pos  = (float*)(ws);                                   // 512 KB
    unsigned short* Xbf  = (unsigned short*)(ws + (512u << 10));           // 8 MB (reused as attb)
    unsigned short* Wbf  = (unsigned short*)(ws + (512u << 10) + (8u  << 20));  // 8 MB (4 stacked)
    unsigned short* qb   = (unsigned short*)(ws + (512u << 10) + (16u << 20));
    unsigned short* kb   = (unsigned short*)(ws + (512u << 10) + (24u << 20));
    unsigned short* vt   = (unsigned short*)(ws + (512u << 10) + (32u << 20));
    unsigned short* attb = Xbf;   // Xbf dead after gemm_qkv; reuse for attn output

    cvt5<<<dim3(4608), dim3(256), 0, stream>>>(X, Wq, Wk, Wv, Wo, Xbf, Wbf, pos);
    gemm_qkv<<<dim3(16, 16), dim3(512), 0, stream>>>(Xbf, Wbf, pos, qb, kb, vt);
    attn_kernel<<<dim3(16, 32), dim3(512), 0, stream>>>(qb, kb, vt, attb);
    gemm_out<<<dim3(32, 16), dim3(128), 0, stream>>>(attb, Wbf, X, out);
}